// Round 2
// baseline (269.365 us; speedup 1.0000x reference)
//
#include <hip/hip_runtime.h>
#include <math.h>

// ---- problem constants ----
#define B_ 2
#define S_ 2048
#define DM_ 2048
#define H_ 16
#define HKV_ 4
#define D_ 128
#define NKV_ 512           // HKV*D
#define M_ 4096            // B*S
#define CHK_ 32            // chunk length
#define NC_ 64             // S/CHK
#define SCALE_ 0.08838834764831845f
#define CLAMP_ 0.95f

typedef unsigned short u16;
typedef u16 ushortx8 __attribute__((ext_vector_type(8)));
typedef __bf16 bf16x8 __attribute__((ext_vector_type(8)));
typedef float f32x4 __attribute__((ext_vector_type(4)));

#define ASYNC16(gsrc, ldst) \
  __builtin_amdgcn_global_load_lds((const __attribute__((address_space(1))) void*)(gsrc), \
                                   (__attribute__((address_space(3))) void*)(ldst), 16, 0, 0)
#define BARRIER() asm volatile("s_barrier" ::: "memory")
#define WAITV(n)  asm volatile("s_waitcnt vmcnt(" #n ")" ::: "memory")

__device__ __forceinline__ u16 f2b(float x){
  unsigned u = __float_as_uint(x);
  return (u16)((u + 0x7FFFu + ((u >> 16) & 1u)) >> 16);
}
__device__ __forceinline__ float b2f(u16 h){
  return __uint_as_float(((unsigned)h) << 16);
}
__device__ __forceinline__ bf16x8 ld8(const u16* p){
  return __builtin_bit_cast(bf16x8, *(const ushortx8*)p);
}
__device__ __forceinline__ f32x4 mfma16(bf16x8 a, bf16x8 b, f32x4 c){
  return __builtin_amdgcn_mfma_f32_16x16x32_bf16(a, b, c, 0, 0, 0);
}

// ---------------- fused f32 -> bf16 convert for hs + Wq + Wk + Wv ----------------
__global__ void k_cvt_all(const float* __restrict__ hs, const float* __restrict__ Wq,
                          const float* __restrict__ Wk, const float* __restrict__ Wv,
                          u16* __restrict__ hsb, u16* __restrict__ wcb){
  int i = blockIdx.x * blockDim.x + threadIdx.x;  // 8-elem unit
  const float* src; u16* dst;
  if (i < 1048576)      { src = hs + (size_t)i * 8;               dst = hsb + (size_t)i * 8; }
  else if (i < 1572864) { int j = i - 1048576; src = Wq + (size_t)j * 8; dst = wcb + (size_t)j * 8; }
  else if (i < 1703936) { int j = i - 1572864; src = Wk + (size_t)j * 8; dst = wcb + 4194304 + (size_t)j * 8; }
  else                  { int j = i - 1703936; src = Wv + (size_t)j * 8; dst = wcb + 5242880 + (size_t)j * 8; }
  const float4* p = (const float4*)src;
  float4 a = p[0], c = p[1];
  ushortx8 o;
  o[0]=f2b(a.x); o[1]=f2b(a.y); o[2]=f2b(a.z); o[3]=f2b(a.w);
  o[4]=f2b(c.x); o[5]=f2b(c.y); o[6]=f2b(c.z); o[7]=f2b(c.w);
  *(ushortx8*)dst = o;
}

// ---------------- 256x256x64 8-wave pipelined GEMM, fused q/k/v epilogue ----------------
// A [4096][2048] bf16, W [3072][2048] bf16. Dynamic LDS 128 KiB:
// [buf(2)][mat(2)][khalf(2)][256 rows][32 cols] bf16, swizzled 16B slots.
__launch_bounds__(512, 2)
__global__ void k_gemm256(const u16* __restrict__ A, const u16* __restrict__ W,
                          const float* __restrict__ bq, const float* __restrict__ bk,
                          const float* __restrict__ bv,
                          u16* __restrict__ qp, u16* __restrict__ kp,
                          float* __restrict__ gG, u16* __restrict__ vT){
  extern __shared__ u16 lds[];
  const int tid = threadIdx.x;
  const int wid = tid >> 6, lane = tid & 63;
  const int m0 = blockIdx.y * 256, n0 = blockIdx.x * 256;
  const int wr = (wid >> 2) * 128, wc = (wid & 3) * 64;
  const int lr = lane & 15, slot = lane >> 4;

  // fragment LDS element offsets within a [256][32] khalf block (XOR-swizzled 16B slots)
  int offA[8], offB[4];
  #pragma unroll
  for (int m = 0; m < 8; ++m){
    int row = wr + m * 16 + lr;
    offA[m] = row * 32 + ((slot ^ (row & 3) ^ ((row >> 2) & 3)) << 3);
  }
  #pragma unroll
  for (int n = 0; n < 4; ++n){
    int row = wc + n * 16 + lr;
    offB[n] = row * 32 + ((slot ^ (row & 3) ^ ((row >> 2) & 3)) << 3);
  }
  // staging: thread t writes LDS linear (row = t>>2, slotL = t&3); inverse swizzle on source col
  const int rowc = tid >> 2;
  const int colx = (((tid & 3) ^ ((tid >> 2) & 3) ^ ((tid >> 4) & 3)) << 3);

  f32x4 acc[8][4] = {};

  // prologue: stage K-tile 0 (Ak0, Bk0, Ak1, Bk1) into buf0
  {
    u16* nx = lds;
    ASYNC16(A + (size_t)(m0 + rowc) * 2048 + 0 + colx,         nx + 0 + wid * 512);
    ASYNC16(A + (size_t)(m0 + 128 + rowc) * 2048 + 0 + colx,   nx + 4096 + wid * 512);
    ASYNC16(W + (size_t)(n0 + rowc) * 2048 + 0 + colx,         nx + 16384 + wid * 512);
    ASYNC16(W + (size_t)(n0 + 128 + rowc) * 2048 + 0 + colx,   nx + 20480 + wid * 512);
    ASYNC16(A + (size_t)(m0 + rowc) * 2048 + 32 + colx,        nx + 8192 + wid * 512);
    ASYNC16(A + (size_t)(m0 + 128 + rowc) * 2048 + 32 + colx,  nx + 12288 + wid * 512);
    ASYNC16(W + (size_t)(n0 + rowc) * 2048 + 32 + colx,        nx + 24576 + wid * 512);
    ASYNC16(W + (size_t)(n0 + 128 + rowc) * 2048 + 32 + colx,  nx + 28672 + wid * 512);
  }
  WAITV(4);
  BARRIER();

  for (int kt = 0; kt < 32; ++kt){
    u16* cur = lds + (kt & 1) * 32768;
    u16* nxt = lds + ((kt & 1) ^ 1) * 32768;
    const int ktn = (kt < 31) ? kt + 1 : 31;   // last iter: harmless dup re-stage
    const int c0 = ktn * 64;
    bf16x8 af[4], bfv[4];

    // ---- P1: kh0 x m0-3 ; stage next Ak0+Bk0 ----
    #pragma unroll
    for (int m = 0; m < 4; ++m) af[m] = ld8(cur + offA[m]);
    #pragma unroll
    for (int n = 0; n < 4; ++n) bfv[n] = ld8(cur + 16384 + offB[n]);
    ASYNC16(A + (size_t)(m0 + rowc) * 2048 + c0 + colx,        nxt + 0 + wid * 512);
    ASYNC16(A + (size_t)(m0 + 128 + rowc) * 2048 + c0 + colx,  nxt + 4096 + wid * 512);
    ASYNC16(W + (size_t)(n0 + rowc) * 2048 + c0 + colx,        nxt + 16384 + wid * 512);
    ASYNC16(W + (size_t)(n0 + 128 + rowc) * 2048 + c0 + colx,  nxt + 20480 + wid * 512);
    BARRIER();
    __builtin_amdgcn_s_setprio(1);
    #pragma unroll
    for (int m = 0; m < 4; ++m)
      #pragma unroll
      for (int n = 0; n < 4; ++n) acc[m][n] = mfma16(af[m], bfv[n], acc[m][n]);
    __builtin_amdgcn_s_setprio(0);
    BARRIER();

    // ---- P2: kh0 x m4-7 ; stage next Ak1+Bk1 ; counted wait ----
    #pragma unroll
    for (int m = 0; m < 4; ++m) af[m] = ld8(cur + offA[m + 4]);
    ASYNC16(A + (size_t)(m0 + rowc) * 2048 + c0 + 32 + colx,       nxt + 8192 + wid * 512);
    ASYNC16(A + (size_t)(m0 + 128 + rowc) * 2048 + c0 + 32 + colx, nxt + 12288 + wid * 512);
    ASYNC16(W + (size_t)(n0 + rowc) * 2048 + c0 + 32 + colx,       nxt + 24576 + wid * 512);
    ASYNC16(W + (size_t)(n0 + 128 + rowc) * 2048 + c0 + 32 + colx, nxt + 28672 + wid * 512);
    BARRIER();
    __builtin_amdgcn_s_setprio(1);
    #pragma unroll
    for (int m = 0; m < 4; ++m)
      #pragma unroll
      for (int n = 0; n < 4; ++n) acc[m + 4][n] = mfma16(af[m], bfv[n], acc[m + 4][n]);
    __builtin_amdgcn_s_setprio(0);
    WAITV(8);    // drains prev-iter Ak1/Bk1 stages -> P3 reads safe after barrier
    BARRIER();

    // ---- P3: kh1 x m0-3 ----
    #pragma unroll
    for (int m = 0; m < 4; ++m) af[m] = ld8(cur + 8192 + offA[m]);
    #pragma unroll
    for (int n = 0; n < 4; ++n) bfv[n] = ld8(cur + 24576 + offB[n]);
    BARRIER();
    __builtin_amdgcn_s_setprio(1);
    #pragma unroll
    for (int m = 0; m < 4; ++m)
      #pragma unroll
      for (int n = 0; n < 4; ++n) acc[m][n] = mfma16(af[m], bfv[n], acc[m][n]);
    __builtin_amdgcn_s_setprio(0);
    BARRIER();

    // ---- P4: kh1 x m4-7 ; counted wait ----
    #pragma unroll
    for (int m = 0; m < 4; ++m) af[m] = ld8(cur + 8192 + offA[m + 4]);
    BARRIER();
    __builtin_amdgcn_s_setprio(1);
    #pragma unroll
    for (int m = 0; m < 4; ++m)
      #pragma unroll
      for (int n = 0; n < 4; ++n) acc[m + 4][n] = mfma16(af[m], bfv[n], acc[m + 4][n]);
    __builtin_amdgcn_s_setprio(0);
    WAITV(4);    // drains this-iter Ak0/Bk0 stages -> next P1 reads safe after barrier
    BARRIER();
  }

  // ---- epilogue: per-region bias + activation ----
  const int lg4 = lane >> 4;
  const int bx = blockIdx.x;
  if (bx < 8){                        // q: relu * scale
    #pragma unroll
    for (int n = 0; n < 4; ++n){
      const int col = n0 + wc + n * 16 + lr;
      const float bb = bq[col];
      #pragma unroll
      for (int m = 0; m < 8; ++m){
        const int rb = m0 + wr + m * 16 + lg4 * 4;
        #pragma unroll
        for (int r = 0; r < 4; ++r){
          float q = fmaxf(acc[m][n][r] + bb, 0.f) * SCALE_;
          qp[(size_t)(rb + r) * DM_ + col] = f2b(q);
        }
      }
    }
  } else if (bx < 10){                // k: kf = min(sigmoid,0.95); g = log1p(-kf)
    #pragma unroll
    for (int n = 0; n < 4; ++n){
      const int cc = n0 - DM_ + wc + n * 16 + lr;
      const float bb = bk[cc];
      #pragma unroll
      for (int m = 0; m < 8; ++m){
        const int rb = m0 + wr + m * 16 + lg4 * 4;
        #pragma unroll
        for (int r = 0; r < 4; ++r){
          float x = acc[m][n][r] + bb;
          float kf = fminf(1.f / (1.f + __expf(-x)), CLAMP_);
          kp[(size_t)(rb + r) * NKV_ + cc] = f2b(kf);
          gG[(size_t)(rb + r) * NKV_ + cc] = log1pf(-kf);
        }
      }
    }
  } else {                            // v: write transposed vT[b][kv][e][s]
    #pragma unroll
    for (int n = 0; n < 4; ++n){
      const int cc = n0 - DM_ - NKV_ + wc + n * 16 + lr;
      const float bias = bv[cc];
      const int kv = cc >> 7, e = cc & 127;
      #pragma unroll
      for (int m = 0; m < 8; ++m){
        const int rb = m0 + wr + m * 16 + lg4 * 4;
        const int bb_ = rb >> 11;
        const int srow = rb & 2047;
        ushort4 pk;
        pk.x = f2b(acc[m][n][0] + bias);
        pk.y = f2b(acc[m][n][1] + bias);
        pk.z = f2b(acc[m][n][2] + bias);
        pk.w = f2b(acc[m][n][3] + bias);
        *(ushort4*)(vT + (((size_t)(bb_ * HKV_ + kv) * D_ + e) * S_ + srow)) = pk;
      }
    }
  }
}

// ---------------- per-chunk inclusive cumsum of g (in place) + chunk decay ----------------
__global__ void k_cumsum(float* __restrict__ g, float* __restrict__ dec){
  const int c = blockIdx.x, b = blockIdx.y;
  const int col = threadIdx.x;        // 512 = kv*128+d
  const size_t base = ((size_t)b * S_ + (size_t)c * CHK_) * NKV_ + col;
  float v[CHK_];
  #pragma unroll
  for (int t = 0; t < CHK_; ++t) v[t] = g[base + (size_t)t * NKV_];
  float acc = 0.f;
  #pragma unroll
  for (int t = 0; t < CHK_; ++t){ acc += v[t]; v[t] = acc; }
  #pragma unroll
  for (int t = 0; t < CHK_; ++t) g[base + (size_t)t * NKV_] = v[t];
  const int kv = col >> 7, d = col & 127;
  dec[(((size_t)b * HKV_ + kv) * NC_ + c) * D_ + d] = __expf(acc);
}

// ---------------- per-chunk state contribution:  SSt[c][e][d] = sum_t v[t][e]*kf[t][d]*exp(G31-G_t) ----------------
__launch_bounds__(256, 2)
__global__ void k_dstate(const u16* __restrict__ kp, const float* __restrict__ G,
                         const u16* __restrict__ vT, u16* __restrict__ SSt){
  __shared__ float kex[CHK_][D_];
  __shared__ float vl[D_][CHK_ + 1];
  const int c = blockIdx.x, kv = blockIdx.y, b = blockIdx.z;
  const int tid = threadIdx.x;
  const int s0 = c * CHK_;
  const size_t gbase = ((size_t)b * S_ + s0) * NKV_ + kv * D_;
  for (int idx = tid; idx < CHK_ * D_; idx += 256){
    const int t = idx >> 7, d = idx & 127;
    const float Gt  = G[gbase + (size_t)t  * NKV_ + d];
    const float G31 = G[gbase + (size_t)31 * NKV_ + d];
    const float kf = b2f(kp[gbase + (size_t)t * NKV_ + d]);
    kex[t][d] = kf * __expf(G31 - Gt);
  }
  const size_t vbase = ((size_t)(b * HKV_ + kv) * D_) * S_ + s0;
  for (int idx = tid; idx < 512; idx += 256){
    const int e = idx >> 2, t8 = (idx & 3) * 8;
    ushortx8 vv = *(const ushortx8*)(vT + vbase + (size_t)e * S_ + t8);
    #pragma unroll
    for (int u = 0; u < 8; ++u) vl[e][t8 + u] = b2f(vv[u]);
  }
  __syncthreads();
  const int w = tid >> 6, lane = tid & 63;
  const int e = (w & 1) * 64 + lane;
  const int d0 = (w >> 1) * 64;
  float acc[64];
  #pragma unroll
  for (int i = 0; i < 64; ++i) acc[i] = 0.f;
  for (int t = 0; t < CHK_; ++t){
    const float vv = vl[e][t];
    const float4* kr = (const float4*)(&kex[t][d0]);
    #pragma unroll
    for (int i4 = 0; i4 < 16; ++i4){
      float4 kk = kr[i4];
      acc[i4*4+0] = fmaf(vv, kk.x, acc[i4*4+0]);
      acc[i4*4+1] = fmaf(vv, kk.y, acc[i4*4+1]);
      acc[i4*4+2] = fmaf(vv, kk.z, acc[i4*4+2]);
      acc[i4*4+3] = fmaf(vv, kk.w, acc[i4*4+3]);
    }
  }
  const size_t ob = (((size_t)(b * HKV_ + kv) * NC_ + c) * D_ + e) * D_ + d0;
  #pragma unroll
  for (int i8 = 0; i8 < 8; ++i8){
    ushortx8 o;
    #pragma unroll
    for (int u = 0; u < 8; ++u) o[u] = f2b(acc[i8*8 + u]);
    *(ushortx8*)(SSt + ob + i8*8) = o;
  }
}

// ---------------- elementwise scan over chunks (in place: dS -> S_start) ----------------
__global__ void k_scan(u16* __restrict__ SSt, const float* __restrict__ dec){
  const int eg = blockIdx.x, kv = blockIdx.y, b = blockIdx.z;
  const int tid = threadIdx.x;
  const int e = eg * 8 + (tid >> 5);
  const int d4 = (tid & 31) * 4;
  const size_t base  = ((size_t)(b * HKV_ + kv) * NC_) * D_ * D_ + (size_t)e * D_ + d4;
  const size_t dbase = ((size_t)(b * HKV_ + kv) * NC_) * D_ + d4;
  float s0 = 0.f, s1 = 0.f, s2 = 0.f, s3 = 0.f;
  for (int c = 0; c < NC_; ++c){
    const size_t off = base + (size_t)c * (D_ * D_);
    ushort4 dv = *(ushort4*)(SSt + off);
    float4 dc = *(const float4*)(dec + dbase + (size_t)c * D_);
    ushort4 wr;
    wr.x = f2b(s0); wr.y = f2b(s1); wr.z = f2b(s2); wr.w = f2b(s3);
    *(ushort4*)(SSt + off) = wr;
    s0 = s0 * dc.x + b2f(dv.x);
    s1 = s1 * dc.y + b2f(dv.y);
    s2 = s2 * dc.z + b2f(dv.z);
    s3 = s3 * dc.w + b2f(dv.w);
  }
}

// ---------------- output: O = (q e^G) @ S_start + masked-decayed QK^T @ V ----------------
__launch_bounds__(256, 2)
__global__ void k_out(const u16* __restrict__ qp, const u16* __restrict__ kp,
                      const float* __restrict__ G, const u16* __restrict__ vT,
                      const u16* __restrict__ SSt, float* __restrict__ out){
  __shared__ u16 QeF[32 * 128];
  __shared__ u16 Qe1[16 * 128];
  __shared__ u16 Ke0[16 * 128];
  __shared__ u16 Ke1[32 * 128];
  __shared__ u16 Sb[128 * 128];
  __shared__ u16 Am[32 * 32];
  __shared__ float G15[128];
  const int c = blockIdx.x, h = blockIdx.y, b = blockIdx.z;
  const int kv = h >> 2;
  const int tid = threadIdx.x, wid = tid >> 6, lane = tid & 63;
  const int s0 = c * CHK_;
  const int lr = lane & 15, lk = (lane >> 4) * 8;
  const size_t gb = ((size_t)b * S_ + s0) * NKV_ + kv * D_;
  const size_t qb = ((size_t)b * S_ + s0) * DM_ + h * D_;
  const size_t vb = ((size_t)(b * HKV_ + kv) * D_) * S_ + s0;
  if (tid < 128) G15[tid] = G[gb + (size_t)15 * NKV_ + tid];
  __syncthreads();
  for (int idx = tid; idx < 32 * 128; idx += 256){
    const int t = idx >> 7, d = idx & 127;
    const float Gt = G[gb + (size_t)t * NKV_ + d];
    const float q = b2f(qp[qb + (size_t)t * DM_ + d]);
    QeF[idx] = f2b(q * __expf(Gt));
    if (t >= 16) Qe1[(t - 16) * 128 + d] = f2b(q * __expf(Gt - G15[d]));
    const float kf = b2f(kp[gb + (size_t)t * NKV_ + d]);
    if (t < 16) Ke0[idx] = f2b(kf * __expf(-Gt));
    Ke1[idx] = f2b(kf * __expf(G15[d] - Gt));
  }
  {
    const u16* src = SSt + (((size_t)(b * HKV_ + kv) * NC_ + c) * (D_ * D_));
    #pragma unroll
    for (int is = 0; is < 8; ++is){
      const int fo = is * 2048 + wid * 512;
      ASYNC16(src + fo + lane * 8, ((u16*)Sb) + fo);
    }
  }
  __syncthreads();
  if (wid == 1){
    for (int i = lane; i < 256; i += 64) Am[(i >> 4) * 32 + 16 + (i & 15)] = 0;
  } else {
    const u16* aQ = (wid == 0) ? QeF : Qe1;
    const u16* aK = (wid == 0) ? Ke0 : Ke1;
    const int tauBase = (wid == 3) ? 16 : 0;
    f32x4 a4 = {};
    #pragma unroll
    for (int kd = 0; kd < 4; ++kd){
      bf16x8 fa = ld8(&aQ[lr * 128 + kd * 32 + lk]);
      bf16x8 fb = ld8(&aK[(tauBase + lr) * 128 + kd * 32 + lk]);
      a4 = mfma16(fa, fb, a4);
    }
    const int rowb = (wid == 0) ? 0 : 16;
    const int colb = (wid == 3) ? 16 : 0;
    const bool diag = (wid == 0) || (wid == 3);
    #pragma unroll
    for (int r = 0; r < 4; ++r){
      const int rr = (lane >> 4) * 4 + r;
      float v = a4[r];
      if (diag && lr > rr) v = 0.f;
      Am[(rowb + rr) * 32 + colb + lr] = f2b(v);
    }
  }
  __syncthreads();
  f32x4 o4[2][2] = {};
  const int ew = wid * 32;
  #pragma unroll
  for (int kd = 0; kd < 4; ++kd){
    bf16x8 fa0 = ld8(&QeF[(0  + lr) * 128 + kd * 32 + lk]);
    bf16x8 fa1 = ld8(&QeF[(16 + lr) * 128 + kd * 32 + lk]);
    bf16x8 fb0 = ld8(&Sb[(ew + lr) * 128 + kd * 32 + lk]);
    bf16x8 fb1 = ld8(&Sb[(ew + 16 + lr) * 128 + kd * 32 + lk]);
    o4[0][0] = mfma16(fa0, fb0, o4[0][0]);
    o4[0][1] = mfma16(fa0, fb1, o4[0][1]);
    o4[1][0] = mfma16(fa1, fb0, o4[1][0]);
    o4[1][1] = mfma16(fa1, fb1, o4[1][1]);
  }
  {
    bf16x8 fa0 = ld8(&Am[lr * 32 + lk]);
    bf16x8 fa1 = ld8(&Am[(16 + lr) * 32 + lk]);
    const u16* vr0 = vT + vb + (size_t)(ew + lr) * S_;
    const u16* vr1 = vT + vb + (size_t)(ew + 16 + lr) * S_;
    bf16x8 fb0 = ld8(vr0 + lk);
    bf16x8 fb1 = ld8(vr1 + lk);
    o4[0][0] = mfma16(fa0, fb0, o4[0][0]);
    o4[0][1] = mfma16(fa0, fb1, o4[0][1]);
    o4[1][0] = mfma16(fa1, fb0, o4[1][0]);
    o4[1][1] = mfma16(fa1, fb1, o4[1][1]);
  }
  #pragma unroll
  for (int i2 = 0; i2 < 2; ++i2)
    #pragma unroll
    for (int j2 = 0; j2 < 2; ++j2)
      #pragma unroll
      for (int r = 0; r < 4; ++r){
        const int t = i2 * 16 + (lane >> 4) * 4 + r;
        const int e = ew + j2 * 16 + lr;
        out[((size_t)b * S_ + s0 + t) * DM_ + h * D_ + e] = o4[i2][j2][r];
      }
}

// ---------------- host launch ----------------
extern "C" void kernel_launch(void* const* d_in, const int* in_sizes, int n_in,
                              void* d_out, int out_size, void* d_ws, size_t ws_size,
                              hipStream_t stream){
  const float* hs = (const float*)d_in[0];
  const float* Wq = (const float*)d_in[1];
  const float* bq = (const float*)d_in[2];
  const float* Wk = (const float*)d_in[3];
  const float* bk = (const float*)d_in[4];
  const float* Wv = (const float*)d_in[5];
  const float* bv = (const float*)d_in[6];
  char* ws = (char*)d_ws;
  u16*   hsb = (u16*)(ws);
  u16*   wcb = (u16*)(ws + 16777216);
  u16*   qp  = (u16*)(ws + 29360128);
  u16*   kp  = (u16*)(ws + 46137344);
  float* gG  = (float*)(ws + 50331648);
  u16*   vT  = (u16*)(ws + 58720256);
  float* dec = (float*)(ws + 62914560);
  u16*   SSt = (u16*)(ws + 63176704);
  float* out = (float*)d_out;

  hipFuncSetAttribute((const void*)k_gemm256,
                      hipFuncAttributeMaxDynamicSharedMemorySize, 131072);

  k_cvt_all<<<dim3(7168), 256, 0, stream>>>(hs, Wq, Wk, Wv, hsb, wcb);
  k_gemm256<<<dim3(12, 16), 512, 131072, stream>>>(hsb, wcb, bq, bk, bv, qp, kp, gG, vT);
  k_cumsum<<<dim3(NC_, B_), 512, 0, stream>>>(gG, dec);
  k_dstate<<<dim3(NC_, HKV_, B_), 256, 0, stream>>>(kp, gG, vT, SSt);
  k_scan<<<dim3(16, HKV_, B_), 256, 0, stream>>>(SSt, dec);
  k_out<<<dim3(NC_, H_, B_), 256, 0, stream>>>(qp, kp, gG, vT, SSt, out);
}

// Round 3
// 265.369 us; speedup vs baseline: 1.0151x; 1.0151x over previous
//
#include <hip/hip_runtime.h>
#include <math.h>

// ---- problem constants ----
#define B_ 2
#define S_ 2048
#define DM_ 2048
#define H_ 16
#define HKV_ 4
#define D_ 128
#define NKV_ 512           // HKV*D
#define M_ 4096            // B*S
#define CHK_ 32            // chunk length
#define NC_ 64             // S/CHK
#define SCALE_ 0.08838834764831845f
#define CLAMP_ 0.95f

typedef unsigned short u16;
typedef u16 ushortx8 __attribute__((ext_vector_type(8)));
typedef __bf16 bf16x8 __attribute__((ext_vector_type(8)));
typedef float f32x4 __attribute__((ext_vector_type(4)));

#define ASYNC16(gsrc, ldst) \
  __builtin_amdgcn_global_load_lds((const __attribute__((address_space(1))) void*)(gsrc), \
                                   (__attribute__((address_space(3))) void*)(ldst), 16, 0, 0)
#define SBAR()    __builtin_amdgcn_s_barrier()
#define WAITV(n)  asm volatile("s_waitcnt vmcnt(" #n ")" ::: "memory")

__device__ __forceinline__ u16 f2b(float x){
  unsigned u = __float_as_uint(x);
  return (u16)((u + 0x7FFFu + ((u >> 16) & 1u)) >> 16);
}
__device__ __forceinline__ float b2f(u16 h){
  return __uint_as_float(((unsigned)h) << 16);
}
__device__ __forceinline__ bf16x8 ld8(const u16* p){
  return __builtin_bit_cast(bf16x8, *(const ushortx8*)p);
}
__device__ __forceinline__ f32x4 mfma16(bf16x8 a, bf16x8 b, f32x4 c){
  return __builtin_amdgcn_mfma_f32_16x16x32_bf16(a, b, c, 0, 0, 0);
}

// ---------------- fused f32 -> bf16 convert for hs + Wq + Wk + Wv ----------------
__global__ void k_cvt_all(const float* __restrict__ hs, const float* __restrict__ Wq,
                          const float* __restrict__ Wk, const float* __restrict__ Wv,
                          u16* __restrict__ hsb, u16* __restrict__ wcb){
  int i = blockIdx.x * blockDim.x + threadIdx.x;  // 8-elem unit
  const float* src; u16* dst;
  if (i < 1048576)      { src = hs + (size_t)i * 8;               dst = hsb + (size_t)i * 8; }
  else if (i < 1572864) { int j = i - 1048576; src = Wq + (size_t)j * 8; dst = wcb + (size_t)j * 8; }
  else if (i < 1703936) { int j = i - 1572864; src = Wk + (size_t)j * 8; dst = wcb + 4194304 + (size_t)j * 8; }
  else                  { int j = i - 1703936; src = Wv + (size_t)j * 8; dst = wcb + 5242880 + (size_t)j * 8; }
  const float4* p = (const float4*)src;
  float4 a = p[0], c = p[1];
  ushortx8 o;
  o[0]=f2b(a.x); o[1]=f2b(a.y); o[2]=f2b(a.z); o[3]=f2b(a.w);
  o[4]=f2b(c.x); o[5]=f2b(c.y); o[6]=f2b(c.z); o[7]=f2b(c.w);
  *(ushortx8*)dst = o;
}

// ---------------- 256x256x64 8-wave pipelined GEMM, fused q/k/v epilogue ----------------
// A [4096][2048] bf16, W [3072][2048] bf16. Dynamic LDS 128 KiB.
// waves_per_eu(2,2): 1 block/CU (LDS-bound anyway) -> full 256-reg unified budget, no spill.
__attribute__((amdgpu_waves_per_eu(2, 2)))
__global__ void __launch_bounds__(512)
k_gemm256(const u16* __restrict__ A, const u16* __restrict__ W,
          const float* __restrict__ bq, const float* __restrict__ bk,
          const float* __restrict__ bv,
          u16* __restrict__ qp, u16* __restrict__ kp,
          float* __restrict__ gG, u16* __restrict__ vT){
  extern __shared__ u16 lds[];
  const int tid = threadIdx.x;
  const int wid = tid >> 6, lane = tid & 63;
  int wg = blockIdx.x;
  wg = (wg & 7) * 24 + (wg >> 3);          // XCD-chunked (192 = 8*24, bijective)
  const int nt = wg % 12;
  const int m0 = (wg / 12) * 256, n0 = nt * 256;
  const int wr = (wid >> 2) * 128, wc = (wid & 3) * 64;
  const int lr = lane & 15, slot = lane >> 4;

  // fragment LDS element offsets within a [256][32] khalf block (XOR-swizzled 16B slots)
  int offA[8], offB[4];
  #pragma unroll
  for (int m = 0; m < 8; ++m){
    int row = wr + m * 16 + lr;
    offA[m] = row * 32 + ((slot ^ (row & 3) ^ ((row >> 2) & 3)) << 3);
  }
  #pragma unroll
  for (int n = 0; n < 4; ++n){
    int row = wc + n * 16 + lr;
    offB[n] = row * 32 + ((slot ^ (row & 3) ^ ((row >> 2) & 3)) << 3);
  }
  // staging: thread t writes LDS linear (row = t>>2); inverse swizzle on source col
  const int rowc = tid >> 2;
  const int colx = (((tid & 3) ^ ((tid >> 2) & 3) ^ ((tid >> 4) & 3)) << 3);
  const u16* gA0 = A + (size_t)(m0 + rowc) * 2048 + colx;
  const u16* gA1 = gA0 + (size_t)128 * 2048;
  const u16* gW0 = W + (size_t)(n0 + rowc) * 2048 + colx;
  const u16* gW1 = gW0 + (size_t)128 * 2048;
  const int ldst = wid * 512;

  f32x4 acc[8][4] = {};

  // prologue: stage K-tile 0 (kh0 then kh1) into buf0
  ASYNC16(gA0 +  0, lds +     0 + ldst);
  ASYNC16(gA1 +  0, lds +  4096 + ldst);
  ASYNC16(gW0 +  0, lds + 16384 + ldst);
  ASYNC16(gW1 +  0, lds + 20480 + ldst);
  ASYNC16(gA0 + 32, lds +  8192 + ldst);
  ASYNC16(gA1 + 32, lds + 12288 + ldst);
  ASYNC16(gW0 + 32, lds + 24576 + ldst);
  ASYNC16(gW1 + 32, lds + 28672 + ldst);
  WAITV(4);
  SBAR();

  for (int kt = 0; kt < 32; ++kt){
    u16* cur = lds + (kt & 1) * 32768;
    u16* nxt = lds + ((kt & 1) ^ 1) * 32768;
    const int c0 = ((kt < 31) ? kt + 1 : 31) * 64;   // last iter: harmless dup re-stage
    bf16x8 af[4], bfv[4];

    // ---- P1: kh0 x m0-3 ; stage next kh0 ----
    #pragma unroll
    for (int m = 0; m < 4; ++m) af[m] = ld8(cur + offA[m]);
    #pragma unroll
    for (int n = 0; n < 4; ++n) bfv[n] = ld8(cur + 16384 + offB[n]);
    ASYNC16(gA0 + c0, nxt +     0 + ldst);
    ASYNC16(gA1 + c0, nxt +  4096 + ldst);
    ASYNC16(gW0 + c0, nxt + 16384 + ldst);
    ASYNC16(gW1 + c0, nxt + 20480 + ldst);
    SBAR();
    __builtin_amdgcn_s_setprio(1);
    #pragma unroll
    for (int m = 0; m < 4; ++m)
      #pragma unroll
      for (int n = 0; n < 4; ++n) acc[m][n] = mfma16(af[m], bfv[n], acc[m][n]);
    __builtin_amdgcn_s_setprio(0);
    SBAR();

    // ---- P2: kh0 x m4-7 ; stage next kh1 ; counted wait ----
    #pragma unroll
    for (int m = 0; m < 4; ++m) af[m] = ld8(cur + offA[m + 4]);
    ASYNC16(gA0 + c0 + 32, nxt +  8192 + ldst);
    ASYNC16(gA1 + c0 + 32, nxt + 12288 + ldst);
    ASYNC16(gW0 + c0 + 32, nxt + 24576 + ldst);
    ASYNC16(gW1 + c0 + 32, nxt + 28672 + ldst);
    SBAR();
    __builtin_amdgcn_s_setprio(1);
    #pragma unroll
    for (int m = 0; m < 4; ++m)
      #pragma unroll
      for (int n = 0; n < 4; ++n) acc[m + 4][n] = mfma16(af[m], bfv[n], acc[m + 4][n]);
    __builtin_amdgcn_s_setprio(0);
    WAITV(8);    // drains prev-iter kh1 stages -> P3 reads safe after barrier
    SBAR();

    // ---- P3: kh1 x m0-3 ----
    #pragma unroll
    for (int m = 0; m < 4; ++m) af[m] = ld8(cur + 8192 + offA[m]);
    #pragma unroll
    for (int n = 0; n < 4; ++n) bfv[n] = ld8(cur + 24576 + offB[n]);
    SBAR();
    __builtin_amdgcn_s_setprio(1);
    #pragma unroll
    for (int m = 0; m < 4; ++m)
      #pragma unroll
      for (int n = 0; n < 4; ++n) acc[m][n] = mfma16(af[m], bfv[n], acc[m][n]);
    __builtin_amdgcn_s_setprio(0);
    SBAR();

    // ---- P4: kh1 x m4-7 ; counted wait ----
    #pragma unroll
    for (int m = 0; m < 4; ++m) af[m] = ld8(cur + 8192 + offA[m + 4]);
    SBAR();
    __builtin_amdgcn_s_setprio(1);
    #pragma unroll
    for (int m = 0; m < 4; ++m)
      #pragma unroll
      for (int n = 0; n < 4; ++n) acc[m + 4][n] = mfma16(af[m], bfv[n], acc[m + 4][n]);
    __builtin_amdgcn_s_setprio(0);
    WAITV(4);    // drains this-iter next-kh0 stages -> next P1 reads safe after barrier
    SBAR();
  }

  // ---- epilogue: per-region bias + activation ----
  const int lg4 = lane >> 4;
  if (nt < 8){                        // q: relu * scale
    #pragma unroll
    for (int n = 0; n < 4; ++n){
      const int col = n0 + wc + n * 16 + lr;
      const float bb = bq[col];
      #pragma unroll
      for (int m = 0; m < 8; ++m){
        const int rb = m0 + wr + m * 16 + lg4 * 4;
        #pragma unroll
        for (int r = 0; r < 4; ++r){
          float q = fmaxf(acc[m][n][r] + bb, 0.f) * SCALE_;
          qp[(size_t)(rb + r) * DM_ + col] = f2b(q);
        }
      }
    }
  } else if (nt < 10){                // k: kf = min(sigmoid,0.95); g = log1p(-kf)
    #pragma unroll
    for (int n = 0; n < 4; ++n){
      const int cc = n0 - DM_ + wc + n * 16 + lr;
      const float bb = bk[cc];
      #pragma unroll
      for (int m = 0; m < 8; ++m){
        const int rb = m0 + wr + m * 16 + lg4 * 4;
        #pragma unroll
        for (int r = 0; r < 4; ++r){
          float x = acc[m][n][r] + bb;
          float kf = fminf(1.f / (1.f + __expf(-x)), CLAMP_);
          kp[(size_t)(rb + r) * NKV_ + cc] = f2b(kf);
          gG[(size_t)(rb + r) * NKV_ + cc] = log1pf(-kf);
        }
      }
    }
  } else {                            // v: write transposed vT[b][kv][e][s]
    #pragma unroll
    for (int n = 0; n < 4; ++n){
      const int cc = n0 - DM_ - NKV_ + wc + n * 16 + lr;
      const float bias = bv[cc];
      const int kv = cc >> 7, e = cc & 127;
      #pragma unroll
      for (int m = 0; m < 8; ++m){
        const int rb = m0 + wr + m * 16 + lg4 * 4;
        const int bb_ = rb >> 11;
        const int srow = rb & 2047;
        ushort4 pk;
        pk.x = f2b(acc[m][n][0] + bias);
        pk.y = f2b(acc[m][n][1] + bias);
        pk.z = f2b(acc[m][n][2] + bias);
        pk.w = f2b(acc[m][n][3] + bias);
        *(ushort4*)(vT + (((size_t)(bb_ * HKV_ + kv) * D_ + e) * S_ + srow)) = pk;
      }
    }
  }
}

// ---------------- per-chunk inclusive cumsum of g (in place) + chunk decay ----------------
__global__ void k_cumsum(float* __restrict__ g, float* __restrict__ dec){
  const int c = blockIdx.x, b = blockIdx.y;
  const int col = threadIdx.x;        // 512 = kv*128+d
  const size_t base = ((size_t)b * S_ + (size_t)c * CHK_) * NKV_ + col;
  float v[CHK_];
  #pragma unroll
  for (int t = 0; t < CHK_; ++t) v[t] = g[base + (size_t)t * NKV_];
  float acc = 0.f;
  #pragma unroll
  for (int t = 0; t < CHK_; ++t){ acc += v[t]; v[t] = acc; }
  #pragma unroll
  for (int t = 0; t < CHK_; ++t) g[base + (size_t)t * NKV_] = v[t];
  const int kv = col >> 7, d = col & 127;
  dec[(((size_t)b * HKV_ + kv) * NC_ + c) * D_ + d] = __expf(acc);
}

// ---------------- per-chunk state contribution:  SSt[c][e][d] = sum_t v[t][e]*kf[t][d]*exp(G31-G_t) ----------------
__launch_bounds__(256, 2)
__global__ void k_dstate(const u16* __restrict__ kp, const float* __restrict__ G,
                         const u16* __restrict__ vT, u16* __restrict__ SSt){
  __shared__ float kex[CHK_][D_];
  __shared__ float vl[D_][CHK_ + 1];
  const int c = blockIdx.x, kv = blockIdx.y, b = blockIdx.z;
  const int tid = threadIdx.x;
  const int s0 = c * CHK_;
  const size_t gbase = ((size_t)b * S_ + s0) * NKV_ + kv * D_;
  for (int idx = tid; idx < CHK_ * D_; idx += 256){
    const int t = idx >> 7, d = idx & 127;
    const float Gt  = G[gbase + (size_t)t  * NKV_ + d];
    const float G31 = G[gbase + (size_t)31 * NKV_ + d];
    const float kf = b2f(kp[gbase + (size_t)t * NKV_ + d]);
    kex[t][d] = kf * __expf(G31 - Gt);
  }
  const size_t vbase = ((size_t)(b * HKV_ + kv) * D_) * S_ + s0;
  for (int idx = tid; idx < 512; idx += 256){
    const int e = idx >> 2, t8 = (idx & 3) * 8;
    ushortx8 vv = *(const ushortx8*)(vT + vbase + (size_t)e * S_ + t8);
    #pragma unroll
    for (int u = 0; u < 8; ++u) vl[e][t8 + u] = b2f(vv[u]);
  }
  __syncthreads();
  const int w = tid >> 6, lane = tid & 63;
  const int e = (w & 1) * 64 + lane;
  const int d0 = (w >> 1) * 64;
  float acc[64];
  #pragma unroll
  for (int i = 0; i < 64; ++i) acc[i] = 0.f;
  for (int t = 0; t < CHK_; ++t){
    const float vv = vl[e][t];
    const float4* kr = (const float4*)(&kex[t][d0]);
    #pragma unroll
    for (int i4 = 0; i4 < 16; ++i4){
      float4 kk = kr[i4];
      acc[i4*4+0] = fmaf(vv, kk.x, acc[i4*4+0]);
      acc[i4*4+1] = fmaf(vv, kk.y, acc[i4*4+1]);
      acc[i4*4+2] = fmaf(vv, kk.z, acc[i4*4+2]);
      acc[i4*4+3] = fmaf(vv, kk.w, acc[i4*4+3]);
    }
  }
  const size_t ob = (((size_t)(b * HKV_ + kv) * NC_ + c) * D_ + e) * D_ + d0;
  #pragma unroll
  for (int i8 = 0; i8 < 8; ++i8){
    ushortx8 o;
    #pragma unroll
    for (int u = 0; u < 8; ++u) o[u] = f2b(acc[i8*8 + u]);
    *(ushortx8*)(SSt + ob + i8*8) = o;
  }
}

// ---------------- elementwise scan over chunks (in place: dS -> S_start) ----------------
__global__ void k_scan(u16* __restrict__ SSt, const float* __restrict__ dec){
  const int eg = blockIdx.x, kv = blockIdx.y, b = blockIdx.z;
  const int tid = threadIdx.x;
  const int e = eg * 8 + (tid >> 5);
  const int d4 = (tid & 31) * 4;
  const size_t base  = ((size_t)(b * HKV_ + kv) * NC_) * D_ * D_ + (size_t)e * D_ + d4;
  const size_t dbase = ((size_t)(b * HKV_ + kv) * NC_) * D_ + d4;
  float s0 = 0.f, s1 = 0.f, s2 = 0.f, s3 = 0.f;
  #pragma unroll 4
  for (int c = 0; c < NC_; ++c){
    const size_t off = base + (size_t)c * (D_ * D_);
    ushort4 dv = *(ushort4*)(SSt + off);
    float4 dc = *(const float4*)(dec + dbase + (size_t)c * D_);
    ushort4 wr;
    wr.x = f2b(s0); wr.y = f2b(s1); wr.z = f2b(s2); wr.w = f2b(s3);
    *(ushort4*)(SSt + off) = wr;
    s0 = s0 * dc.x + b2f(dv.x);
    s1 = s1 * dc.y + b2f(dv.y);
    s2 = s2 * dc.z + b2f(dv.z);
    s3 = s3 * dc.w + b2f(dv.w);
  }
}

// ---------------- output: O = (q e^G) @ S_start + masked-decayed QK^T @ V ----------------
__launch_bounds__(256, 2)
__global__ void k_out(const u16* __restrict__ qp, const u16* __restrict__ kp,
                      const float* __restrict__ G, const u16* __restrict__ vT,
                      const u16* __restrict__ SSt, float* __restrict__ out){
  __shared__ u16 QeF[32 * 128];
  __shared__ u16 Qe1[16 * 128];
  __shared__ u16 Ke0[16 * 128];
  __shared__ u16 Ke1[32 * 128];
  __shared__ u16 Sb[128 * 128];
  __shared__ u16 Am[32 * 32];
  __shared__ float G15[128];
  const int c = blockIdx.x, h = blockIdx.y, b = blockIdx.z;
  const int kv = h >> 2;
  const int tid = threadIdx.x, wid = tid >> 6, lane = tid & 63;
  const int s0 = c * CHK_;
  const int lr = lane & 15, lk = (lane >> 4) * 8;
  const size_t gb = ((size_t)b * S_ + s0) * NKV_ + kv * D_;
  const size_t qb = ((size_t)b * S_ + s0) * DM_ + h * D_;
  const size_t vb = ((size_t)(b * HKV_ + kv) * D_) * S_ + s0;
  if (tid < 128) G15[tid] = G[gb + (size_t)15 * NKV_ + tid];
  __syncthreads();
  for (int idx = tid; idx < 32 * 128; idx += 256){
    const int t = idx >> 7, d = idx & 127;
    const float Gt = G[gb + (size_t)t * NKV_ + d];
    const float q = b2f(qp[qb + (size_t)t * DM_ + d]);
    QeF[idx] = f2b(q * __expf(Gt));
    if (t >= 16) Qe1[(t - 16) * 128 + d] = f2b(q * __expf(Gt - G15[d]));
    const float kf = b2f(kp[gb + (size_t)t * NKV_ + d]);
    if (t < 16) Ke0[idx] = f2b(kf * __expf(-Gt));
    Ke1[idx] = f2b(kf * __expf(G15[d] - Gt));
  }
  {
    const u16* src = SSt + (((size_t)(b * HKV_ + kv) * NC_ + c) * (D_ * D_));
    #pragma unroll
    for (int is = 0; is < 8; ++is){
      const int fo = is * 2048 + wid * 512;
      ASYNC16(src + fo + lane * 8, ((u16*)Sb) + fo);
    }
  }
  __syncthreads();
  if (wid == 1){
    for (int i = lane; i < 256; i += 64) Am[(i >> 4) * 32 + 16 + (i & 15)] = 0;
  } else {
    const u16* aQ = (wid == 0) ? QeF : Qe1;
    const u16* aK = (wid == 0) ? Ke0 : Ke1;
    const int tauBase = (wid == 3) ? 16 : 0;
    f32x4 a4 = {};
    #pragma unroll
    for (int kd = 0; kd < 4; ++kd){
      bf16x8 fa = ld8(&aQ[lr * 128 + kd * 32 + lk]);
      bf16x8 fb = ld8(&aK[(tauBase + lr) * 128 + kd * 32 + lk]);
      a4 = mfma16(fa, fb, a4);
    }
    const int rowb = (wid == 0) ? 0 : 16;
    const int colb = (wid == 3) ? 16 : 0;
    const bool diag = (wid == 0) || (wid == 3);
    #pragma unroll
    for (int r = 0; r < 4; ++r){
      const int rr = (lane >> 4) * 4 + r;
      float v = a4[r];
      if (diag && lr > rr) v = 0.f;
      Am[(rowb + rr) * 32 + colb + lr] = f2b(v);
    }
  }
  __syncthreads();
  f32x4 o4[2][2] = {};
  const int ew = wid * 32;
  #pragma unroll
  for (int kd = 0; kd < 4; ++kd){
    bf16x8 fa0 = ld8(&QeF[(0  + lr) * 128 + kd * 32 + lk]);
    bf16x8 fa1 = ld8(&QeF[(16 + lr) * 128 + kd * 32 + lk]);
    bf16x8 fb0 = ld8(&Sb[(ew + lr) * 128 + kd * 32 + lk]);
    bf16x8 fb1 = ld8(&Sb[(ew + 16 + lr) * 128 + kd * 32 + lk]);
    o4[0][0] = mfma16(fa0, fb0, o4[0][0]);
    o4[0][1] = mfma16(fa0, fb1, o4[0][1]);
    o4[1][0] = mfma16(fa1, fb0, o4[1][0]);
    o4[1][1] = mfma16(fa1, fb1, o4[1][1]);
  }
  {
    bf16x8 fa0 = ld8(&Am[lr * 32 + lk]);
    bf16x8 fa1 = ld8(&Am[(16 + lr) * 32 + lk]);
    const u16* vr0 = vT + vb + (size_t)(ew + lr) * S_;
    const u16* vr1 = vT + vb + (size_t)(ew + 16 + lr) * S_;
    bf16x8 fb0 = ld8(vr0 + lk);
    bf16x8 fb1 = ld8(vr1 + lk);
    o4[0][0] = mfma16(fa0, fb0, o4[0][0]);
    o4[0][1] = mfma16(fa0, fb1, o4[0][1]);
    o4[1][0] = mfma16(fa1, fb0, o4[1][0]);
    o4[1][1] = mfma16(fa1, fb1, o4[1][1]);
  }
  #pragma unroll
  for (int i2 = 0; i2 < 2; ++i2)
    #pragma unroll
    for (int j2 = 0; j2 < 2; ++j2)
      #pragma unroll
      for (int r = 0; r < 4; ++r){
        const int t = i2 * 16 + (lane >> 4) * 4 + r;
        const int e = ew + j2 * 16 + lr;
        out[((size_t)b * S_ + s0 + t) * DM_ + h * D_ + e] = o4[i2][j2][r];
      }
}

// ---------------- host launch ----------------
extern "C" void kernel_launch(void* const* d_in, const int* in_sizes, int n_in,
                              void* d_out, int out_size, void* d_ws, size_t ws_size,
                              hipStream_t stream){
  const float* hs = (const float*)d_in[0];
  const float* Wq = (const float*)d_in[1];
  const float* bq = (const float*)d_in[2];
  const float* Wk = (const float*)d_in[3];
  const float* bk = (const float*)d_in[4];
  const float* Wv = (const float*)d_in[5];
  const float* bv = (const float*)d_in[6];
  char* ws = (char*)d_ws;
  u16*   hsb = (u16*)(ws);
  u16*   wcb = (u16*)(ws + 16777216);
  u16*   qp  = (u16*)(ws + 29360128);
  u16*   kp  = (u16*)(ws + 46137344);
  float* gG  = (float*)(ws + 50331648);
  u16*   vT  = (u16*)(ws + 58720256);
  float* dec = (float*)(ws + 62914560);
  u16*   SSt = (u16*)(ws + 63176704);
  float* out = (float*)d_out;

  hipFuncSetAttribute((const void*)k_gemm256,
                      hipFuncAttributeMaxDynamicSharedMemorySize, 131072);

  k_cvt_all<<<dim3(7168), 256, 0, stream>>>(hs, Wq, Wk, Wv, hsb, wcb);
  k_gemm256<<<dim3(192), 512, 131072, stream>>>(hsb, wcb, bq, bk, bv, qp, kp, gG, vT);
  k_cumsum<<<dim3(NC_, B_), 512, 0, stream>>>(gG, dec);
  k_dstate<<<dim3(NC_, HKV_, B_), 256, 0, stream>>>(kp, gG, vT, SSt);
  k_scan<<<dim3(16, HKV_, B_), 256, 0, stream>>>(SSt, dec);
  k_out<<<dim3(NC_, H_, B_), 256, 0, stream>>>(qp, kp, gG, vT, SSt, out);
}

// Round 6
// 200.910 us; speedup vs baseline: 1.3407x; 1.3208x over previous
//
#include <hip/hip_runtime.h>
#include <math.h>

// ---- problem constants ----
#define B_ 2
#define S_ 2048
#define DM_ 2048
#define H_ 16
#define HKV_ 4
#define D_ 128
#define NKV_ 512           // HKV*D
#define M_ 4096            // B*S
#define CHK_ 32            // chunk length
#define NC_ 64             // S/CHK
#define SCALE_ 0.08838834764831845f
#define CLAMP_ 0.95f

typedef unsigned short u16;
typedef u16 ushortx8 __attribute__((ext_vector_type(8)));
typedef __bf16 bf16x8 __attribute__((ext_vector_type(8)));
typedef float f32x4 __attribute__((ext_vector_type(4)));

#define ASYNC16(gsrc, ldst) \
  __builtin_amdgcn_global_load_lds((const __attribute__((address_space(1))) void*)(gsrc), \
                                   (__attribute__((address_space(3))) void*)(ldst), 16, 0, 0)
#define SBAR()    __builtin_amdgcn_s_barrier()
#define WAITV(n)  asm volatile("s_waitcnt vmcnt(" #n ")" ::: "memory")

__device__ __forceinline__ u16 f2b(float x){
  unsigned u = __float_as_uint(x);
  return (u16)((u + 0x7FFFu + ((u >> 16) & 1u)) >> 16);
}
__device__ __forceinline__ float b2f(u16 h){
  return __uint_as_float(((unsigned)h) << 16);
}
__device__ __forceinline__ bf16x8 ld8(const u16* p){
  return __builtin_bit_cast(bf16x8, *(const ushortx8*)p);
}
__device__ __forceinline__ f32x4 mfma16(bf16x8 a, bf16x8 b, f32x4 c){
  return __builtin_amdgcn_mfma_f32_16x16x32_bf16(a, b, c, 0, 0, 0);
}

// ---------------- fused f32 -> bf16 convert for hs + Wq + Wk + Wv ----------------
__global__ void k_cvt_all(const float* __restrict__ hs, const float* __restrict__ Wq,
                          const float* __restrict__ Wk, const float* __restrict__ Wv,
                          u16* __restrict__ hsb, u16* __restrict__ wcb){
  int i = blockIdx.x * blockDim.x + threadIdx.x;  // 8-elem unit
  const float* src; u16* dst;
  if (i < 1048576)      { src = hs + (size_t)i * 8;               dst = hsb + (size_t)i * 8; }
  else if (i < 1572864) { int j = i - 1048576; src = Wq + (size_t)j * 8; dst = wcb + (size_t)j * 8; }
  else if (i < 1703936) { int j = i - 1572864; src = Wk + (size_t)j * 8; dst = wcb + 4194304 + (size_t)j * 8; }
  else                  { int j = i - 1703936; src = Wv + (size_t)j * 8; dst = wcb + 5242880 + (size_t)j * 8; }
  const float4* p = (const float4*)src;
  float4 a = p[0], c = p[1];
  ushortx8 o;
  o[0]=f2b(a.x); o[1]=f2b(a.y); o[2]=f2b(a.z); o[3]=f2b(a.w);
  o[4]=f2b(c.x); o[5]=f2b(c.y); o[6]=f2b(c.z); o[7]=f2b(c.w);
  *(ushortx8*)dst = o;
}

// ---------------- 128x128x64 4-wave GEMM, double-buffered LDS, counted vmcnt ----------------
// A [4096][2048] bf16, W [3072][2048] bf16. Dynamic LDS 64 KiB -> 2 blocks/CU.
// LDS elems: [buf:16384] = [A kh0:4096 | A kh1:4096 | B kh0:4096 | B kh1:4096]
// Per phase (one kh): ds_read frags(cur) ; 4x ASYNC16 stage(nxt,kh) ; 16 MFMA ;
// WAITV(4) retires previous phase's 4 stages ; SBAR. Staged data read 2 phases later.
__launch_bounds__(256, 2)
__global__ void k_gemm(const u16* __restrict__ A, const u16* __restrict__ W,
                       const float* __restrict__ bq, const float* __restrict__ bk,
                       const float* __restrict__ bv,
                       u16* __restrict__ qp, u16* __restrict__ kp,
                       float* __restrict__ gG, u16* __restrict__ vT){
  extern __shared__ u16 lds[];
  const int tid = threadIdx.x;
  const int wid = tid >> 6, lane = tid & 63;
  const int m0 = blockIdx.y * 128, n0 = blockIdx.x * 128;
  const int wr = (wid >> 1) * 64, wc = (wid & 1) * 64;
  const int lr = lane & 15, lk = (lane >> 4) * 8;

  // fragment offsets within a kh-region ([128][32] row-major)
  int offA[4], offB[4];
  #pragma unroll
  for (int m = 0; m < 4; ++m) offA[m] = (wr + m * 16 + lr) * 32 + lk;
  #pragma unroll
  for (int n = 0; n < 4; ++n) offB[n] = (wc + n * 16 + lr) * 32 + lk;

  // staging source (per-lane): row = wid*16 + lane/4, col = (lane&3)*8 within kh region
  const int srow = (wid << 4) + (lane >> 2);
  const int scol = (lane & 3) * 8;
  const u16* gAs = A + (size_t)(m0 + srow) * 2048 + scol;
  const u16* gWs = W + (size_t)(n0 + srow) * 2048 + scol;
  const int ldw = wid << 9;          // wave-uniform LDS sub-offset (elems)

  // STAGE(dstbase elems, kh, colbase): 2 calls A + 2 calls W (c-step = 64 rows = 131072 elems)
#define STAGE_(db, kh, cb) \
  ASYNC16(gAs +          (cb) + (kh)*32, lds + (db) +            (kh)*4096 +        ldw); \
  ASYNC16(gAs + 131072 + (cb) + (kh)*32, lds + (db) +            (kh)*4096 + 2048 + ldw); \
  ASYNC16(gWs +          (cb) + (kh)*32, lds + (db) + 8192 +     (kh)*4096 +        ldw); \
  ASYNC16(gWs + 131072 + (cb) + (kh)*32, lds + (db) + 8192 +     (kh)*4096 + 2048 + ldw)

  f32x4 acc[4][4] = {};

  // prologue: stage tile 0 (both kh halves) into buf0
  STAGE_(0, 0, 0);
  STAGE_(0, 1, 0);
  WAITV(0);
  SBAR();

  for (int kt = 0; kt < 32; ++kt){
    const int cb = (kt & 1) * 16384;           // cur buf base (elems)
    const int nb = cb ^ 16384;                 // next buf base
    const int c0 = ((kt < 31) ? kt + 1 : 31) * 64;   // next K-col; last iter dup-stages (never read)
    #pragma unroll
    for (int kh = 0; kh < 2; ++kh){
      bf16x8 af[4], bfv[4];
      #pragma unroll
      for (int m = 0; m < 4; ++m) af[m]  = ld8(lds + cb + kh * 4096 + offA[m]);
      #pragma unroll
      for (int n = 0; n < 4; ++n) bfv[n] = ld8(lds + cb + 8192 + kh * 4096 + offB[n]);
      STAGE_(nb, kh, c0);
      #pragma unroll
      for (int m = 0; m < 4; ++m)
        #pragma unroll
        for (int n = 0; n < 4; ++n) acc[m][n] = mfma16(af[m], bfv[n], acc[m][n]);
      WAITV(4);    // retire previous phase's 4 stages (their region is read next phase)
      SBAR();
    }
  }
#undef STAGE_

  // ---- epilogue: per-region bias + activation (identical to R1) ----
  const int lg4 = lane >> 4;
  const int tn = blockIdx.x;
  if (tn < 16){                       // ---- q region: relu * scale ----
    #pragma unroll
    for (int i = 0; i < 4; ++i){
      const int rb = m0 + wr + i*16 + lg4*4;
      #pragma unroll
      for (int j = 0; j < 4; ++j){
        const int col = n0 + wc + j*16 + lr;
        const float bb = bq[col];
        #pragma unroll
        for (int r = 0; r < 4; ++r){
          float q = fmaxf(acc[i][j][r] + bb, 0.f) * SCALE_;
          qp[(size_t)(rb + r) * DM_ + col] = f2b(q);
        }
      }
    }
  } else if (tn < 20){                // ---- k region: kf = min(sigmoid,0.95), g = log1p(-kf) ----
    #pragma unroll
    for (int i = 0; i < 4; ++i){
      const int rb = m0 + wr + i*16 + lg4*4;
      #pragma unroll
      for (int j = 0; j < 4; ++j){
        const int cc = n0 - DM_ + wc + j*16 + lr;
        const float bb = bk[cc];
        #pragma unroll
        for (int r = 0; r < 4; ++r){
          float x = acc[i][j][r] + bb;
          float kf = fminf(1.f / (1.f + __expf(-x)), CLAMP_);
          kp[(size_t)(rb + r) * NKV_ + cc] = f2b(kf);
          gG[(size_t)(rb + r) * NKV_ + cc] = log1pf(-kf);
        }
      }
    }
  } else {                            // ---- v region: write transposed vT[b][kv][e][s] ----
    #pragma unroll
    for (int i = 0; i < 4; ++i){
      const int rb = m0 + wr + i*16 + lg4*4;
      const int bb_ = rb >> 11;
      const int srw = rb & 2047;
      #pragma unroll
      for (int j = 0; j < 4; ++j){
        const int cc = n0 - DM_ - NKV_ + wc + j*16 + lr;
        const float bias = bv[cc];
        const int kv = cc >> 7, e = cc & 127;
        ushort4 pk;
        pk.x = f2b(acc[i][j][0] + bias);
        pk.y = f2b(acc[i][j][1] + bias);
        pk.z = f2b(acc[i][j][2] + bias);
        pk.w = f2b(acc[i][j][3] + bias);
        *(ushort4*)(vT + (((size_t)(bb_ * HKV_ + kv) * D_ + e) * S_ + srw)) = pk;
      }
    }
  }
}

// ---------------- per-chunk inclusive cumsum of g (in place) + chunk decay ----------------
__global__ void k_cumsum(float* __restrict__ g, float* __restrict__ dec){
  const int c = blockIdx.x, b = blockIdx.y;
  const int col = threadIdx.x;        // 512 = kv*128+d
  const size_t base = ((size_t)b * S_ + (size_t)c * CHK_) * NKV_ + col;
  float v[CHK_];
  #pragma unroll
  for (int t = 0; t < CHK_; ++t) v[t] = g[base + (size_t)t * NKV_];
  float acc = 0.f;
  #pragma unroll
  for (int t = 0; t < CHK_; ++t){ acc += v[t]; v[t] = acc; }
  #pragma unroll
  for (int t = 0; t < CHK_; ++t) g[base + (size_t)t * NKV_] = v[t];
  const int kv = col >> 7, d = col & 127;
  dec[(((size_t)b * HKV_ + kv) * NC_ + c) * D_ + d] = __expf(acc);
}

// ---------------- per-chunk state contribution:  SSt[c][e][d] = sum_t v[t][e]*kf[t][d]*exp(G31-G_t) ----------------
__launch_bounds__(256, 2)
__global__ void k_dstate(const u16* __restrict__ kp, const float* __restrict__ G,
                         const u16* __restrict__ vT, u16* __restrict__ SSt){
  __shared__ float kex[CHK_][D_];
  __shared__ float vl[D_][CHK_ + 1];
  const int c = blockIdx.x, kv = blockIdx.y, b = blockIdx.z;
  const int tid = threadIdx.x;
  const int s0 = c * CHK_;
  const size_t gbase = ((size_t)b * S_ + s0) * NKV_ + kv * D_;
  for (int idx = tid; idx < CHK_ * D_; idx += 256){
    const int t = idx >> 7, d = idx & 127;
    const float Gt  = G[gbase + (size_t)t  * NKV_ + d];
    const float G31 = G[gbase + (size_t)31 * NKV_ + d];
    const float kf = b2f(kp[gbase + (size_t)t * NKV_ + d]);
    kex[t][d] = kf * __expf(G31 - Gt);
  }
  const size_t vbase = ((size_t)(b * HKV_ + kv) * D_) * S_ + s0;
  for (int idx = tid; idx < 512; idx += 256){
    const int e = idx >> 2, t8 = (idx & 3) * 8;
    ushortx8 vv = *(const ushortx8*)(vT + vbase + (size_t)e * S_ + t8);
    #pragma unroll
    for (int u = 0; u < 8; ++u) vl[e][t8 + u] = b2f(vv[u]);
  }
  __syncthreads();
  const int w = tid >> 6, lane = tid & 63;
  const int e = (w & 1) * 64 + lane;
  const int d0 = (w >> 1) * 64;
  float acc[64];
  #pragma unroll
  for (int i = 0; i < 64; ++i) acc[i] = 0.f;
  for (int t = 0; t < CHK_; ++t){
    const float vv = vl[e][t];
    const float4* kr = (const float4*)(&kex[t][d0]);
    #pragma unroll
    for (int i4 = 0; i4 < 16; ++i4){
      float4 kk = kr[i4];
      acc[i4*4+0] = fmaf(vv, kk.x, acc[i4*4+0]);
      acc[i4*4+1] = fmaf(vv, kk.y, acc[i4*4+1]);
      acc[i4*4+2] = fmaf(vv, kk.z, acc[i4*4+2]);
      acc[i4*4+3] = fmaf(vv, kk.w, acc[i4*4+3]);
    }
  }
  const size_t ob = (((size_t)(b * HKV_ + kv) * NC_ + c) * D_ + e) * D_ + d0;
  #pragma unroll
  for (int i8 = 0; i8 < 8; ++i8){
    ushortx8 o;
    #pragma unroll
    for (int u = 0; u < 8; ++u) o[u] = f2b(acc[i8*8 + u]);
    *(ushortx8*)(SSt + ob + i8*8) = o;
  }
}

// ---------------- elementwise scan over chunks (in place: dS -> S_start) ----------------
__global__ void k_scan(u16* __restrict__ SSt, const float* __restrict__ dec){
  const int eg = blockIdx.x, kv = blockIdx.y, b = blockIdx.z;
  const int tid = threadIdx.x;
  const int e = eg * 8 + (tid >> 5);
  const int d4 = (tid & 31) * 4;
  const size_t base  = ((size_t)(b * HKV_ + kv) * NC_) * D_ * D_ + (size_t)e * D_ + d4;
  const size_t dbase = ((size_t)(b * HKV_ + kv) * NC_) * D_ + d4;
  float s0 = 0.f, s1 = 0.f, s2 = 0.f, s3 = 0.f;
  #pragma unroll 4
  for (int c = 0; c < NC_; ++c){
    const size_t off = base + (size_t)c * (D_ * D_);
    ushort4 dv = *(ushort4*)(SSt + off);
    float4 dc = *(const float4*)(dec + dbase + (size_t)c * D_);
    ushort4 wr;
    wr.x = f2b(s0); wr.y = f2b(s1); wr.z = f2b(s2); wr.w = f2b(s3);
    *(ushort4*)(SSt + off) = wr;
    s0 = s0 * dc.x + b2f(dv.x);
    s1 = s1 * dc.y + b2f(dv.y);
    s2 = s2 * dc.z + b2f(dv.z);
    s3 = s3 * dc.w + b2f(dv.w);
  }
}

// ---------------- output: O = (q e^G) @ S_start + masked-decayed QK^T @ V ----------------
__launch_bounds__(256, 2)
__global__ void k_out(const u16* __restrict__ qp, const u16* __restrict__ kp,
                      const float* __restrict__ G, const u16* __restrict__ vT,
                      const u16* __restrict__ SSt, float* __restrict__ out){
  __shared__ u16 QeF[32 * 128];
  __shared__ u16 Qe1[16 * 128];
  __shared__ u16 Ke0[16 * 128];
  __shared__ u16 Ke1[32 * 128];
  __shared__ u16 Sb[128 * 128];
  __shared__ u16 Am[32 * 32];
  __shared__ float G15[128];
  const int c = blockIdx.x, h = blockIdx.y, b = blockIdx.z;
  const int kv = h >> 2;
  const int tid = threadIdx.x, wid = tid >> 6, lane = tid & 63;
  const int s0 = c * CHK_;
  const int lr = lane & 15, lk = (lane >> 4) * 8;
  const size_t gb = ((size_t)b * S_ + s0) * NKV_ + kv * D_;
  const size_t qb = ((size_t)b * S_ + s0) * DM_ + h * D_;
  const size_t vb = ((size_t)(b * HKV_ + kv) * D_) * S_ + s0;
  if (tid < 128) G15[tid] = G[gb + (size_t)15 * NKV_ + tid];
  __syncthreads();
  for (int idx = tid; idx < 32 * 128; idx += 256){
    const int t = idx >> 7, d = idx & 127;
    const float Gt = G[gb + (size_t)t * NKV_ + d];
    const float q = b2f(qp[qb + (size_t)t * DM_ + d]);
    QeF[idx] = f2b(q * __expf(Gt));
    if (t >= 16) Qe1[(t - 16) * 128 + d] = f2b(q * __expf(Gt - G15[d]));
    const float kf = b2f(kp[gb + (size_t)t * NKV_ + d]);
    if (t < 16) Ke0[idx] = f2b(kf * __expf(-Gt));
    Ke1[idx] = f2b(kf * __expf(G15[d] - Gt));
  }
  {
    const u16* src = SSt + (((size_t)(b * HKV_ + kv) * NC_ + c) * (D_ * D_));
    #pragma unroll
    for (int is = 0; is < 8; ++is){
      const int fo = is * 2048 + wid * 512;
      ASYNC16(src + fo + lane * 8, ((u16*)Sb) + fo);
    }
  }
  __syncthreads();
  if (wid == 1){
    for (int i = lane; i < 256; i += 64) Am[(i >> 4) * 32 + 16 + (i & 15)] = 0;
  } else {
    const u16* aQ = (wid == 0) ? QeF : Qe1;
    const u16* aK = (wid == 0) ? Ke0 : Ke1;
    const int tauBase = (wid == 3) ? 16 : 0;
    f32x4 a4 = {};
    #pragma unroll
    for (int kd = 0; kd < 4; ++kd){
      bf16x8 fa = ld8(&aQ[lr * 128 + kd * 32 + lk]);
      bf16x8 fb = ld8(&aK[(tauBase + lr) * 128 + kd * 32 + lk]);
      a4 = mfma16(fa, fb, a4);
    }
    const int rowb = (wid == 0) ? 0 : 16;
    const int colb = (wid == 3) ? 16 : 0;
    const bool diag = (wid == 0) || (wid == 3);
    #pragma unroll
    for (int r = 0; r < 4; ++r){
      const int rr = (lane >> 4) * 4 + r;
      float v = a4[r];
      if (diag && lr > rr) v = 0.f;
      Am[(rowb + rr) * 32 + colb + lr] = f2b(v);
    }
  }
  __syncthreads();
  f32x4 o4[2][2] = {};
  const int ew = wid * 32;
  #pragma unroll
  for (int kd = 0; kd < 4; ++kd){
    bf16x8 fa0 = ld8(&QeF[(0  + lr) * 128 + kd * 32 + lk]);
    bf16x8 fa1 = ld8(&QeF[(16 + lr) * 128 + kd * 32 + lk]);
    bf16x8 fb0 = ld8(&Sb[(ew + lr) * 128 + kd * 32 + lk]);
    bf16x8 fb1 = ld8(&Sb[(ew + 16 + lr) * 128 + kd * 32 + lk]);
    o4[0][0] = mfma16(fa0, fb0, o4[0][0]);
    o4[0][1] = mfma16(fa0, fb1, o4[0][1]);
    o4[1][0] = mfma16(fa1, fb0, o4[1][0]);
    o4[1][1] = mfma16(fa1, fb1, o4[1][1]);
  }
  {
    bf16x8 fa0 = ld8(&Am[lr * 32 + lk]);
    bf16x8 fa1 = ld8(&Am[(16 + lr) * 32 + lk]);
    const u16* vr0 = vT + vb + (size_t)(ew + lr) * S_;
    const u16* vr1 = vT + vb + (size_t)(ew + 16 + lr) * S_;
    bf16x8 fb0 = ld8(vr0 + lk);
    bf16x8 fb1 = ld8(vr1 + lk);
    o4[0][0] = mfma16(fa0, fb0, o4[0][0]);
    o4[0][1] = mfma16(fa0, fb1, o4[0][1]);
    o4[1][0] = mfma16(fa1, fb0, o4[1][0]);
    o4[1][1] = mfma16(fa1, fb1, o4[1][1]);
  }
  #pragma unroll
  for (int i2 = 0; i2 < 2; ++i2)
    #pragma unroll
    for (int j2 = 0; j2 < 2; ++j2)
      #pragma unroll
      for (int r = 0; r < 4; ++r){
        const int t = i2 * 16 + (lane >> 4) * 4 + r;
        const int e = ew + j2 * 16 + lr;
        out[((size_t)b * S_ + s0 + t) * DM_ + h * D_ + e] = o4[i2][j2][r];
      }
}

// ---------------- host launch ----------------
extern "C" void kernel_launch(void* const* d_in, const int* in_sizes, int n_in,
                              void* d_out, int out_size, void* d_ws, size_t ws_size,
                              hipStream_t stream){
  const float* hs = (const float*)d_in[0];
  const float* Wq = (const float*)d_in[1];
  const float* bq = (const float*)d_in[2];
  const float* Wk = (const float*)d_in[3];
  const float* bk = (const float*)d_in[4];
  const float* Wv = (const float*)d_in[5];
  const float* bv = (const float*)d_in[6];
  char* ws = (char*)d_ws;
  u16*   hsb = (u16*)(ws);
  u16*   wcb = (u16*)(ws + 16777216);
  u16*   qp  = (u16*)(ws + 29360128);
  u16*   kp  = (u16*)(ws + 46137344);
  float* gG  = (float*)(ws + 50331648);
  u16*   vT  = (u16*)(ws + 58720256);
  float* dec = (float*)(ws + 62914560);
  u16*   SSt = (u16*)(ws + 63176704);
  float* out = (float*)d_out;

  hipFuncSetAttribute((const void*)k_gemm,
                      hipFuncAttributeMaxDynamicSharedMemorySize, 65536);

  k_cvt_all<<<dim3(7168), 256, 0, stream>>>(hs, Wq, Wk, Wv, hsb, wcb);
  k_gemm<<<dim3(24, 32), 256, 65536, stream>>>(hsb, wcb, bq, bk, bv, qp, kp, gG, vT);
  k_cumsum<<<dim3(NC_, B_), 512, 0, stream>>>(gG, dec);
  k_dstate<<<dim3(NC_, HKV_, B_), 256, 0, stream>>>(kp, gG, vT, SSt);
  k_scan<<<dim3(16, HKV_, B_), 256, 0, stream>>>(SSt, dec);
  k_out<<<dim3(NC_, H_, B_), 256, 0, stream>>>(qp, kp, gG, vT, SSt, out);
}

// Round 7
// 152.116 us; speedup vs baseline: 1.7708x; 1.3208x over previous
//
#include <hip/hip_runtime.h>
#include <math.h>

// ---- problem constants ----
#define B_ 2
#define S_ 2048
#define DM_ 2048
#define H_ 16
#define HKV_ 4
#define D_ 128
#define NKV_ 512           // HKV*D
#define M_ 4096            // B*S
#define CHK_ 32            // chunk length
#define NC_ 64             // S/CHK
#define SCALE_ 0.08838834764831845f
#define CLAMP_ 0.95f

typedef unsigned short u16;
typedef u16 ushortx8 __attribute__((ext_vector_type(8)));
typedef __bf16 bf16x8 __attribute__((ext_vector_type(8)));
typedef float f32x4 __attribute__((ext_vector_type(4)));

#define ASYNC16(gsrc, ldst) \
  __builtin_amdgcn_global_load_lds((const __attribute__((address_space(1))) void*)(gsrc), \
                                   (__attribute__((address_space(3))) void*)(ldst), 16, 0, 0)

__device__ __forceinline__ u16 f2b(float x){
  unsigned u = __float_as_uint(x);
  return (u16)((u + 0x7FFFu + ((u >> 16) & 1u)) >> 16);
}
__device__ __forceinline__ float b2f(u16 h){
  return __uint_as_float(((unsigned)h) << 16);
}
__device__ __forceinline__ bf16x8 ld8(const u16* p){
  return __builtin_bit_cast(bf16x8, *(const ushortx8*)p);
}
__device__ __forceinline__ f32x4 mfma16(bf16x8 a, bf16x8 b, f32x4 c){
  return __builtin_amdgcn_mfma_f32_16x16x32_bf16(a, b, c, 0, 0, 0);
}

// ---------------- fused f32 -> bf16 convert for hs + Wq + Wk + Wv ----------------
__global__ void k_cvt_all(const float* __restrict__ hs, const float* __restrict__ Wq,
                          const float* __restrict__ Wk, const float* __restrict__ Wv,
                          u16* __restrict__ hsb, u16* __restrict__ wcb){
  int i = blockIdx.x * blockDim.x + threadIdx.x;  // 8-elem unit
  const float* src; u16* dst;
  if (i < 1048576)      { src = hs + (size_t)i * 8;               dst = hsb + (size_t)i * 8; }
  else if (i < 1572864) { int j = i - 1048576; src = Wq + (size_t)j * 8; dst = wcb + (size_t)j * 8; }
  else if (i < 1703936) { int j = i - 1572864; src = Wk + (size_t)j * 8; dst = wcb + 4194304 + (size_t)j * 8; }
  else                  { int j = i - 1703936; src = Wv + (size_t)j * 8; dst = wcb + 5242880 + (size_t)j * 8; }
  const float4* p = (const float4*)src;
  float4 a = p[0], c = p[1];
  ushortx8 o;
  o[0]=f2b(a.x); o[1]=f2b(a.y); o[2]=f2b(a.z); o[3]=f2b(a.w);
  o[4]=f2b(c.x); o[5]=f2b(c.y); o[6]=f2b(c.z); o[7]=f2b(c.w);
  *(ushortx8*)dst = o;
}

// ---------------- R1-proven 128x128x32 GEMM, fused q/k/v epilogue ----------------
__launch_bounds__(256, 2)
__global__ void k_gemm(const u16* __restrict__ A, const u16* __restrict__ W,
                       const float* __restrict__ bq, const float* __restrict__ bk,
                       const float* __restrict__ bv,
                       u16* __restrict__ qp, u16* __restrict__ kp,
                       float* __restrict__ gG, u16* __restrict__ vT){
  __shared__ u16 Al[128 * 32];
  __shared__ u16 Bl[128 * 32];
  const int tid = threadIdx.x;
  const int wid = tid >> 6, lane = tid & 63;
  const int m0 = blockIdx.y * 128, n0 = blockIdx.x * 128;
  const int wr = (wid >> 1) * 64, wc = (wid & 1) * 64;
  const int lr = lane & 15, lk = (lane >> 4) * 8;
  f32x4 acc[4][4] = {};
  for (int kt = 0; kt < 64; ++kt){
    const int k0 = kt * 32;
    #pragma unroll
    for (int s = 0; s < 2; ++s){
      const int fo = (wid * 2 + s) * 512;   // wave-uniform LDS base (elems)
      const int el = fo + lane * 8;
      const int row = el >> 5, kk = el & 31;
      ASYNC16(A + (size_t)(m0 + row) * DM_ + k0 + kk, Al + fo);
      ASYNC16(W + (size_t)(n0 + row) * DM_ + k0 + kk, Bl + fo);
    }
    __syncthreads();
    bf16x8 af[4], bfr[4];
    #pragma unroll
    for (int i = 0; i < 4; ++i) af[i]  = ld8(&Al[(wr + i*16 + lr)*32 + lk]);
    #pragma unroll
    for (int j = 0; j < 4; ++j) bfr[j] = ld8(&Bl[(wc + j*16 + lr)*32 + lk]);
    #pragma unroll
    for (int i = 0; i < 4; ++i)
      #pragma unroll
      for (int j = 0; j < 4; ++j)
        acc[i][j] = mfma16(af[i], bfr[j], acc[i][j]);
    __syncthreads();
  }
  const int lg4 = lane >> 4;
  const int tn = blockIdx.x;
  if (tn < 16){                       // ---- q region: relu * scale ----
    #pragma unroll
    for (int i = 0; i < 4; ++i){
      const int rb = m0 + wr + i*16 + lg4*4;
      #pragma unroll
      for (int j = 0; j < 4; ++j){
        const int col = n0 + wc + j*16 + lr;
        const float bb = bq[col];
        #pragma unroll
        for (int r = 0; r < 4; ++r){
          float q = fmaxf(acc[i][j][r] + bb, 0.f) * SCALE_;
          qp[(size_t)(rb + r) * DM_ + col] = f2b(q);
        }
      }
    }
  } else if (tn < 20){                // ---- k region ----
    #pragma unroll
    for (int i = 0; i < 4; ++i){
      const int rb = m0 + wr + i*16 + lg4*4;
      #pragma unroll
      for (int j = 0; j < 4; ++j){
        const int cc = n0 - DM_ + wc + j*16 + lr;
        const float bb = bk[cc];
        #pragma unroll
        for (int r = 0; r < 4; ++r){
          float x = acc[i][j][r] + bb;
          float kf = fminf(1.f / (1.f + __expf(-x)), CLAMP_);
          kp[(size_t)(rb + r) * NKV_ + cc] = f2b(kf);
          gG[(size_t)(rb + r) * NKV_ + cc] = log1pf(-kf);
        }
      }
    }
  } else {                            // ---- v region: write transposed vT[b][kv][e][s] ----
    #pragma unroll
    for (int i = 0; i < 4; ++i){
      const int rb = m0 + wr + i*16 + lg4*4;
      const int bb_ = rb >> 11;
      const int srow = rb & 2047;
      #pragma unroll
      for (int j = 0; j < 4; ++j){
        const int cc = n0 - DM_ - NKV_ + wc + j*16 + lr;
        const float bias = bv[cc];
        const int kv = cc >> 7, e = cc & 127;
        ushort4 pk;
        pk.x = f2b(acc[i][j][0] + bias);
        pk.y = f2b(acc[i][j][1] + bias);
        pk.z = f2b(acc[i][j][2] + bias);
        pk.w = f2b(acc[i][j][3] + bias);
        *(ushort4*)(vT + (((size_t)(bb_ * HKV_ + kv) * D_ + e) * S_ + srow)) = pk;
      }
    }
  }
}

// ---------------- per-chunk inclusive cumsum of g (in place) + chunk decay ----------------
__global__ void k_cumsum(float* __restrict__ g, float* __restrict__ dec){
  const int c = blockIdx.x, b = blockIdx.y;
  const int col = threadIdx.x;        // 512 = kv*128+d
  const size_t base = ((size_t)b * S_ + (size_t)c * CHK_) * NKV_ + col;
  float v[CHK_];
  #pragma unroll
  for (int t = 0; t < CHK_; ++t) v[t] = g[base + (size_t)t * NKV_];
  float acc = 0.f;
  #pragma unroll
  for (int t = 0; t < CHK_; ++t){ acc += v[t]; v[t] = acc; }
  #pragma unroll
  for (int t = 0; t < CHK_; ++t) g[base + (size_t)t * NKV_] = v[t];
  const int kv = col >> 7, d = col & 127;
  dec[(((size_t)b * HKV_ + kv) * NC_ + c) * D_ + d] = __expf(acc);
}

// ---------------- per-chunk state contribution:  SSt[c][e][d] = sum_t v[t][e]*kf[t][d]*exp(G31-G_t) ----------------
__launch_bounds__(256, 2)
__global__ void k_dstate(const u16* __restrict__ kp, const float* __restrict__ G,
                         const u16* __restrict__ vT, u16* __restrict__ SSt){
  __shared__ float kex[CHK_][D_];
  __shared__ float vl[D_][CHK_ + 1];
  const int c = blockIdx.x, kv = blockIdx.y, b = blockIdx.z;
  const int tid = threadIdx.x;
  const int s0 = c * CHK_;
  const size_t gbase = ((size_t)b * S_ + s0) * NKV_ + kv * D_;
  for (int idx = tid; idx < CHK_ * D_; idx += 256){
    const int t = idx >> 7, d = idx & 127;
    const float Gt  = G[gbase + (size_t)t  * NKV_ + d];
    const float G31 = G[gbase + (size_t)31 * NKV_ + d];
    const float kf = b2f(kp[gbase + (size_t)t * NKV_ + d]);
    kex[t][d] = kf * __expf(G31 - Gt);
  }
  const size_t vbase = ((size_t)(b * HKV_ + kv) * D_) * S_ + s0;
  for (int idx = tid; idx < 512; idx += 256){
    const int e = idx >> 2, t8 = (idx & 3) * 8;
    ushortx8 vv = *(const ushortx8*)(vT + vbase + (size_t)e * S_ + t8);
    #pragma unroll
    for (int u = 0; u < 8; ++u) vl[e][t8 + u] = b2f(vv[u]);
  }
  __syncthreads();
  const int w = tid >> 6, lane = tid & 63;
  const int e = (w & 1) * 64 + lane;
  const int d0 = (w >> 1) * 64;
  float acc[64];
  #pragma unroll
  for (int i = 0; i < 64; ++i) acc[i] = 0.f;
  for (int t = 0; t < CHK_; ++t){
    const float vv = vl[e][t];
    const float4* kr = (const float4*)(&kex[t][d0]);
    #pragma unroll
    for (int i4 = 0; i4 < 16; ++i4){
      float4 kk = kr[i4];
      acc[i4*4+0] = fmaf(vv, kk.x, acc[i4*4+0]);
      acc[i4*4+1] = fmaf(vv, kk.y, acc[i4*4+1]);
      acc[i4*4+2] = fmaf(vv, kk.z, acc[i4*4+2]);
      acc[i4*4+3] = fmaf(vv, kk.w, acc[i4*4+3]);
    }
  }
  const size_t ob = (((size_t)(b * HKV_ + kv) * NC_ + c) * D_ + e) * D_ + d0;
  #pragma unroll
  for (int i8 = 0; i8 < 8; ++i8){
    ushortx8 o;
    #pragma unroll
    for (int u = 0; u < 8; ++u) o[u] = f2b(acc[i8*8 + u]);
    *(ushortx8*)(SSt + ob + i8*8) = o;
  }
}

// ---------------- elementwise scan over chunks (in place: dS -> S_start) ----------------
__global__ void k_scan(u16* __restrict__ SSt, const float* __restrict__ dec){
  const int eg = blockIdx.x, kv = blockIdx.y, b = blockIdx.z;
  const int tid = threadIdx.x;
  const int e = eg * 8 + (tid >> 5);
  const int d4 = (tid & 31) * 4;
  const size_t base  = ((size_t)(b * HKV_ + kv) * NC_) * D_ * D_ + (size_t)e * D_ + d4;
  const size_t dbase = ((size_t)(b * HKV_ + kv) * NC_) * D_ + d4;
  float s0 = 0.f, s1 = 0.f, s2 = 0.f, s3 = 0.f;
  #pragma unroll 4
  for (int c = 0; c < NC_; ++c){
    const size_t off = base + (size_t)c * (D_ * D_);
    ushort4 dv = *(ushort4*)(SSt + off);
    float4 dc = *(const float4*)(dec + dbase + (size_t)c * D_);
    ushort4 wr;
    wr.x = f2b(s0); wr.y = f2b(s1); wr.z = f2b(s2); wr.w = f2b(s3);
    *(ushort4*)(SSt + off) = wr;
    s0 = s0 * dc.x + b2f(dv.x);
    s1 = s1 * dc.y + b2f(dv.y);
    s2 = s2 * dc.z + b2f(dv.z);
    s3 = s3 * dc.w + b2f(dv.w);
  }
}

// ---------------- output, per-kv blocks: 4 heads share Sb/Ke/G ----------------
// LDS (u16 elems): Sb 0..16384 | Ke0 16384..18432 | Ke1 18432..22528 |
// QeF_h 22528+hh*4096 | Qe1_h 38912+hh*2048 | Am_h 47104+hh*1024 | G15f @51200 (256)
#define L_SB   0
#define L_KE0  16384
#define L_KE1  18432
#define L_QEF  22528
#define L_QE1  38912
#define L_AM   47104
#define L_G15  51200
__global__ void __launch_bounds__(512)
k_out2(const u16* __restrict__ qp, const u16* __restrict__ kp,
       const float* __restrict__ G, const u16* __restrict__ vT,
       const u16* __restrict__ SSt, float* __restrict__ out){
  extern __shared__ u16 lds[];
  float* G15f = (float*)(lds + L_G15);
  const int c = blockIdx.x, kv = blockIdx.y, b = blockIdx.z;
  const int tid = threadIdx.x, wid = tid >> 6, lane = tid & 63;
  const int hh = wid >> 1, sub = wid & 1;
  const int s0 = c * CHK_;
  const int lr = lane & 15, lk = (lane >> 4) * 8;
  const size_t gb = ((size_t)b * S_ + s0) * NKV_ + kv * D_;
  const size_t qb0 = ((size_t)b * S_ + s0) * DM_ + (kv * 4) * D_;
  const size_t vb = ((size_t)(b * HKV_ + kv) * D_) * S_ + s0;

  // Sb staging first (DMA overlaps the exp-heavy fill below)
  {
    const u16* src = SSt + (((size_t)(b * HKV_ + kv) * NC_ + c) * (D_ * D_));
    #pragma unroll
    for (int is = 0; is < 4; ++is){
      const int fo = is * 4096 + wid * 512;
      ASYNC16(src + fo + lane * 8, lds + L_SB + fo);
    }
  }
  if (tid < 128) G15f[tid] = G[gb + (size_t)15 * NKV_ + tid];
  __syncthreads();

  // fill QeF/Qe1 (per head) + Ke0/Ke1 (shared): 4096 idx, 8 iters
  for (int idx = tid; idx < 32 * 128; idx += 512){
    const int t = idx >> 7, d = idx & 127;
    const float Gt = G[gb + (size_t)t * NKV_ + d];
    const float kf = b2f(kp[gb + (size_t)t * NKV_ + d]);
    const float eGt = __expf(Gt);
    float qv[4];
    #pragma unroll
    for (int q4 = 0; q4 < 4; ++q4) qv[q4] = b2f(qp[qb0 + (size_t)t * DM_ + q4 * D_ + d]);
    #pragma unroll
    for (int q4 = 0; q4 < 4; ++q4) lds[L_QEF + q4 * 4096 + idx] = f2b(qv[q4] * eGt);
    if (t >= 16){
      const float r = __expf(Gt - G15f[d]);
      #pragma unroll
      for (int q4 = 0; q4 < 4; ++q4) lds[L_QE1 + q4 * 2048 + (t - 16) * 128 + d] = f2b(qv[q4] * r);
    }
    if (t < 16) lds[L_KE0 + idx] = f2b(kf * __expf(-Gt));
    lds[L_KE1 + idx] = f2b(kf * __expf(G15f[d] - Gt));
  }
  __syncthreads();

  // ---- intra score blocks for this wave's head ----
  const u16* QeF = lds + L_QEF + hh * 4096;
  const u16* Qe1 = lds + L_QE1 + hh * 2048;
  u16* Am = lds + L_AM + hh * 1024;
  if (sub == 0){
    f32x4 aU = {}, aL = {};
    #pragma unroll
    for (int kd = 0; kd < 4; ++kd){
      bf16x8 faU = ld8(&QeF[lr * 128 + kd * 32 + lk]);
      bf16x8 fbU = ld8(&lds[L_KE0 + lr * 128 + kd * 32 + lk]);
      aU = mfma16(faU, fbU, aU);
      bf16x8 faL = ld8(&Qe1[lr * 128 + kd * 32 + lk]);
      bf16x8 fbL = ld8(&lds[L_KE1 + (16 + lr) * 128 + kd * 32 + lk]);
      aL = mfma16(faL, fbL, aL);
    }
    #pragma unroll
    for (int r = 0; r < 4; ++r){
      const int rr = (lane >> 4) * 4 + r;
      float vU = aU[r]; if (lr > rr) vU = 0.f;
      Am[rr * 32 + lr] = f2b(vU);
      float vL = aL[r]; if (lr > rr) vL = 0.f;
      Am[(16 + rr) * 32 + 16 + lr] = f2b(vL);
    }
  } else {
    f32x4 aO = {};
    #pragma unroll
    for (int kd = 0; kd < 4; ++kd){
      bf16x8 fa = ld8(&Qe1[lr * 128 + kd * 32 + lk]);
      bf16x8 fb = ld8(&lds[L_KE1 + lr * 128 + kd * 32 + lk]);
      aO = mfma16(fa, fb, aO);
    }
    #pragma unroll
    for (int r = 0; r < 4; ++r){
      const int rr = (lane >> 4) * 4 + r;
      Am[(16 + rr) * 32 + lr] = f2b(aO[r]);
    }
    for (int i = lane; i < 256; i += 64) Am[(i >> 4) * 32 + 16 + (i & 15)] = 0;
  }
  __syncthreads();

  // ---- O = QeF @ Sb + Am @ V : this wave covers 64 e-cols (sub*64) ----
  f32x4 o4[2][4] = {};
  const int ew = sub * 64;
  #pragma unroll
  for (int kd = 0; kd < 4; ++kd){
    bf16x8 fa0 = ld8(&QeF[(0  + lr) * 128 + kd * 32 + lk]);
    bf16x8 fa1 = ld8(&QeF[(16 + lr) * 128 + kd * 32 + lk]);
    #pragma unroll
    for (int j2 = 0; j2 < 4; ++j2){
      bf16x8 fb = ld8(&lds[L_SB + (ew + j2 * 16 + lr) * 128 + kd * 32 + lk]);
      o4[0][j2] = mfma16(fa0, fb, o4[0][j2]);
      o4[1][j2] = mfma16(fa1, fb, o4[1][j2]);
    }
  }
  {
    bf16x8 fa0 = ld8(&Am[lr * 32 + lk]);
    bf16x8 fa1 = ld8(&Am[(16 + lr) * 32 + lk]);
    #pragma unroll
    for (int j2 = 0; j2 < 4; ++j2){
      const u16* vr = vT + vb + (size_t)(ew + j2 * 16 + lr) * S_;
      bf16x8 fb = ld8(vr + lk);
      o4[0][j2] = mfma16(fa0, fb, o4[0][j2]);
      o4[1][j2] = mfma16(fa1, fb, o4[1][j2]);
    }
  }
  const int hD = (kv * 4 + hh) * D_;
  #pragma unroll
  for (int i2 = 0; i2 < 2; ++i2)
    #pragma unroll
    for (int j2 = 0; j2 < 4; ++j2)
      #pragma unroll
      for (int r = 0; r < 4; ++r){
        const int t = i2 * 16 + (lane >> 4) * 4 + r;
        const int e = ew + j2 * 16 + lr;
        out[((size_t)b * S_ + s0 + t) * DM_ + hD + e] = o4[i2][j2][r];
      }
}

// ---------------- host launch ----------------
extern "C" void kernel_launch(void* const* d_in, const int* in_sizes, int n_in,
                              void* d_out, int out_size, void* d_ws, size_t ws_size,
                              hipStream_t stream){
  const float* hs = (const float*)d_in[0];
  const float* Wq = (const float*)d_in[1];
  const float* bq = (const float*)d_in[2];
  const float* Wk = (const float*)d_in[3];
  const float* bk = (const float*)d_in[4];
  const float* Wv = (const float*)d_in[5];
  const float* bv = (const float*)d_in[6];
  char* ws = (char*)d_ws;
  u16*   hsb = (u16*)(ws);
  u16*   wcb = (u16*)(ws + 16777216);
  u16*   qp  = (u16*)(ws + 29360128);
  u16*   kp  = (u16*)(ws + 46137344);
  float* gG  = (float*)(ws + 50331648);
  u16*   vT  = (u16*)(ws + 58720256);
  float* dec = (float*)(ws + 62914560);
  u16*   SSt = (u16*)(ws + 63176704);
  float* out = (float*)d_out;

  hipFuncSetAttribute((const void*)k_out2,
                      hipFuncAttributeMaxDynamicSharedMemorySize, 102912);

  k_cvt_all<<<dim3(7168), 256, 0, stream>>>(hs, Wq, Wk, Wv, hsb, wcb);
  k_gemm<<<dim3(24, 32), 256, 0, stream>>>(hsb, wcb, bq, bk, bv, qp, kp, gG, vT);
  k_cumsum<<<dim3(NC_, B_), 512, 0, stream>>>(gG, dec);
  k_dstate<<<dim3(NC_, HKV_, B_), 256, 0, stream>>>(kp, gG, vT, SSt);
  k_scan<<<dim3(16, HKV_, B_), 256, 0, stream>>>(SSt, dec);
  k_out2<<<dim3(NC_, HKV_, B_), 512, 102912, stream>>>(qp, kp, gG, vT, SSt, out);
}

// Round 8
// 151.886 us; speedup vs baseline: 1.7735x; 1.0015x over previous
//
#include <hip/hip_runtime.h>
#include <math.h>

// ---- problem constants ----
#define B_ 2
#define S_ 2048
#define DM_ 2048
#define H_ 16
#define HKV_ 4
#define D_ 128
#define NKV_ 512           // HKV*D
#define M_ 4096            // B*S
#define CHK_ 32            // chunk length
#define NC_ 64             // S/CHK
#define SCALE_ 0.08838834764831845f
#define CLAMP_ 0.95f

typedef unsigned short u16;
typedef u16 ushortx8 __attribute__((ext_vector_type(8)));
typedef __bf16 bf16x8 __attribute__((ext_vector_type(8)));
typedef float f32x4 __attribute__((ext_vector_type(4)));

#define ASYNC16(gsrc, ldst) \
  __builtin_amdgcn_global_load_lds((const __attribute__((address_space(1))) void*)(gsrc), \
                                   (__attribute__((address_space(3))) void*)(ldst), 16, 0, 0)
#define SBAR()    __builtin_amdgcn_s_barrier()
#define WAITV(n)  asm volatile("s_waitcnt vmcnt(" #n ")" ::: "memory")

__device__ __forceinline__ u16 f2b(float x){
  unsigned u = __float_as_uint(x);
  return (u16)((u + 0x7FFFu + ((u >> 16) & 1u)) >> 16);
}
__device__ __forceinline__ float b2f(u16 h){
  return __uint_as_float(((unsigned)h) << 16);
}
__device__ __forceinline__ bf16x8 ld8(const u16* p){
  return __builtin_bit_cast(bf16x8, *(const ushortx8*)p);
}
__device__ __forceinline__ f32x4 mfma16(bf16x8 a, bf16x8 b, f32x4 c){
  return __builtin_amdgcn_mfma_f32_16x16x32_bf16(a, b, c, 0, 0, 0);
}

// ---------------- fused f32 -> bf16 convert for hs + Wq + Wk + Wv ----------------
__global__ void k_cvt_all(const float* __restrict__ hs, const float* __restrict__ Wq,
                          const float* __restrict__ Wk, const float* __restrict__ Wv,
                          u16* __restrict__ hsb, u16* __restrict__ wcb){
  int i = blockIdx.x * blockDim.x + threadIdx.x;  // 8-elem unit
  const float* src; u16* dst;
  if (i < 1048576)      { src = hs + (size_t)i * 8;               dst = hsb + (size_t)i * 8; }
  else if (i < 1572864) { int j = i - 1048576; src = Wq + (size_t)j * 8; dst = wcb + (size_t)j * 8; }
  else if (i < 1703936) { int j = i - 1572864; src = Wk + (size_t)j * 8; dst = wcb + 4194304 + (size_t)j * 8; }
  else                  { int j = i - 1703936; src = Wv + (size_t)j * 8; dst = wcb + 5242880 + (size_t)j * 8; }
  const float4* p = (const float4*)src;
  float4 a = p[0], c = p[1];
  ushortx8 o;
  o[0]=f2b(a.x); o[1]=f2b(a.y); o[2]=f2b(a.z); o[3]=f2b(a.w);
  o[4]=f2b(c.x); o[5]=f2b(c.y); o[6]=f2b(c.z); o[7]=f2b(c.w);
  *(ushortx8*)dst = o;
}

// ---------------- 128x128x32 GEMM, 3-slot LDS ring, counted vmcnt, 1 barrier/K-step ----------------
// Slot s (16 KiB): A tile [128][32] at s*8192, B tile at s*8192+4096 (elems).
// Iter kt: WAITV(4) retires tile-kt batch (issued at kt-2) ; SBAR ;
//          stage tile kt+2 -> slot (kt+2)%3 ; ds_read tile kt ; 16 MFMA.
// Slot reuse distance = 3 iters; barrier separates last read from overwrite.
__launch_bounds__(256, 2)
__global__ void k_gemm(const u16* __restrict__ A, const u16* __restrict__ W,
                       const float* __restrict__ bq, const float* __restrict__ bk,
                       const float* __restrict__ bv,
                       u16* __restrict__ qp, u16* __restrict__ kp,
                       float* __restrict__ gG, u16* __restrict__ vT){
  __shared__ u16 L[3 * 8192];          // 48 KiB -> 2 blocks/CU
  const int tid = threadIdx.x;
  const int wid = tid >> 6, lane = tid & 63;
  const int m0 = blockIdx.y * 128, n0 = blockIdx.x * 128;
  const int wr = (wid >> 1) * 64, wc = (wid & 1) * 64;
  const int lr = lane & 15, lk = (lane >> 4) * 8;

  int offA[4], offB[4];
  #pragma unroll
  for (int m = 0; m < 4; ++m) offA[m] = (wr + m * 16 + lr) * 32 + lk;
  #pragma unroll
  for (int n = 0; n < 4; ++n) offB[n] = (wc + n * 16 + lr) * 32 + lk;

  // staging: per-lane source row/col; wave-uniform LDS dest (hardware adds lane*16B)
  const int srow = wid * 32 + (lane >> 2);
  const int scol = (lane & 3) * 8;
  const u16* gA = A + (size_t)(m0 + srow) * DM_ + scol;
  const u16* gW = W + (size_t)(n0 + srow) * DM_ + scol;
  const int fo = wid * 1024;

#define STG(db, kk0) \
  ASYNC16(gA + (kk0),             L + (db) + fo); \
  ASYNC16(gA + 16 * DM_ + (kk0),  L + (db) + fo + 512); \
  ASYNC16(gW + (kk0),             L + (db) + 4096 + fo); \
  ASYNC16(gW + 16 * DM_ + (kk0),  L + (db) + 4096 + fo + 512)

  f32x4 acc[4][4] = {};

  // prologue: tile0 -> slot0, tile1 -> slot1
  STG(0, 0);
  STG(8192, 32);

  int sl_cur = 0, sl_st = 16384;
  for (int kt = 0; kt < 64; ++kt){
    WAITV(4);          // tile kt's 4 loads (issued at kt-2) retired
    SBAR();
    const int k2 = ((kt + 2 < 64) ? kt + 2 : 63) * 32;
    STG(sl_st, k2);    // issue-early; lands in slot (kt+2)%3
    bf16x8 af[4], bfv[4];
    #pragma unroll
    for (int m = 0; m < 4; ++m) af[m]  = ld8(L + sl_cur + offA[m]);
    #pragma unroll
    for (int n = 0; n < 4; ++n) bfv[n] = ld8(L + sl_cur + 4096 + offB[n]);
    #pragma unroll
    for (int m = 0; m < 4; ++m)
      #pragma unroll
      for (int n = 0; n < 4; ++n)
        acc[m][n] = mfma16(af[m], bfv[n], acc[m][n]);
    sl_cur = (sl_cur == 16384) ? 0 : sl_cur + 8192;
    sl_st  = (sl_st  == 16384) ? 0 : sl_st  + 8192;
  }
#undef STG

  // ---- epilogue: per-region bias + activation (R1-proven) ----
  const int lg4 = lane >> 4;
  const int tn = blockIdx.x;
  if (tn < 16){                       // ---- q region: relu * scale ----
    #pragma unroll
    for (int i = 0; i < 4; ++i){
      const int rb = m0 + wr + i*16 + lg4*4;
      #pragma unroll
      for (int j = 0; j < 4; ++j){
        const int col = n0 + wc + j*16 + lr;
        const float bb = bq[col];
        #pragma unroll
        for (int r = 0; r < 4; ++r){
          float q = fmaxf(acc[i][j][r] + bb, 0.f) * SCALE_;
          qp[(size_t)(rb + r) * DM_ + col] = f2b(q);
        }
      }
    }
  } else if (tn < 20){                // ---- k region ----
    #pragma unroll
    for (int i = 0; i < 4; ++i){
      const int rb = m0 + wr + i*16 + lg4*4;
      #pragma unroll
      for (int j = 0; j < 4; ++j){
        const int cc = n0 - DM_ + wc + j*16 + lr;
        const float bb = bk[cc];
        #pragma unroll
        for (int r = 0; r < 4; ++r){
          float x = acc[i][j][r] + bb;
          float kf = fminf(1.f / (1.f + __expf(-x)), CLAMP_);
          kp[(size_t)(rb + r) * NKV_ + cc] = f2b(kf);
          gG[(size_t)(rb + r) * NKV_ + cc] = log1pf(-kf);
        }
      }
    }
  } else {                            // ---- v region: write transposed vT[b][kv][e][s] ----
    #pragma unroll
    for (int i = 0; i < 4; ++i){
      const int rb = m0 + wr + i*16 + lg4*4;
      const int bb_ = rb >> 11;
      const int srw = rb & 2047;
      #pragma unroll
      for (int j = 0; j < 4; ++j){
        const int cc = n0 - DM_ - NKV_ + wc + j*16 + lr;
        const float bias = bv[cc];
        const int kv = cc >> 7, e = cc & 127;
        ushort4 pk;
        pk.x = f2b(acc[i][j][0] + bias);
        pk.y = f2b(acc[i][j][1] + bias);
        pk.z = f2b(acc[i][j][2] + bias);
        pk.w = f2b(acc[i][j][3] + bias);
        *(ushort4*)(vT + (((size_t)(bb_ * HKV_ + kv) * D_ + e) * S_ + srw)) = pk;
      }
    }
  }
}

// ---------------- per-chunk inclusive cumsum of g (in place) + chunk decay ----------------
__global__ void k_cumsum(float* __restrict__ g, float* __restrict__ dec){
  const int c = blockIdx.x, b = blockIdx.y;
  const int col = threadIdx.x;        // 512 = kv*128+d
  const size_t base = ((size_t)b * S_ + (size_t)c * CHK_) * NKV_ + col;
  float v[CHK_];
  #pragma unroll
  for (int t = 0; t < CHK_; ++t) v[t] = g[base + (size_t)t * NKV_];
  float acc = 0.f;
  #pragma unroll
  for (int t = 0; t < CHK_; ++t){ acc += v[t]; v[t] = acc; }
  #pragma unroll
  for (int t = 0; t < CHK_; ++t) g[base + (size_t)t * NKV_] = v[t];
  const int kv = col >> 7, d = col & 127;
  dec[(((size_t)b * HKV_ + kv) * NC_ + c) * D_ + d] = __expf(acc);
}

// ---------------- per-chunk state contribution:  SSt[c][e][d] = sum_t v[t][e]*kf[t][d]*exp(G31-G_t) ----------------
__launch_bounds__(256, 2)
__global__ void k_dstate(const u16* __restrict__ kp, const float* __restrict__ G,
                         const u16* __restrict__ vT, u16* __restrict__ SSt){
  __shared__ float kex[CHK_][D_];
  __shared__ float vl[D_][CHK_ + 1];
  const int c = blockIdx.x, kv = blockIdx.y, b = blockIdx.z;
  const int tid = threadIdx.x;
  const int s0 = c * CHK_;
  const size_t gbase = ((size_t)b * S_ + s0) * NKV_ + kv * D_;
  for (int idx = tid; idx < CHK_ * D_; idx += 256){
    const int t = idx >> 7, d = idx & 127;
    const float Gt  = G[gbase + (size_t)t  * NKV_ + d];
    const float G31 = G[gbase + (size_t)31 * NKV_ + d];
    const float kf = b2f(kp[gbase + (size_t)t * NKV_ + d]);
    kex[t][d] = kf * __expf(G31 - Gt);
  }
  const size_t vbase = ((size_t)(b * HKV_ + kv) * D_) * S_ + s0;
  for (int idx = tid; idx < 512; idx += 256){
    const int e = idx >> 2, t8 = (idx & 3) * 8;
    ushortx8 vv = *(const ushortx8*)(vT + vbase + (size_t)e * S_ + t8);
    #pragma unroll
    for (int u = 0; u < 8; ++u) vl[e][t8 + u] = b2f(vv[u]);
  }
  __syncthreads();
  const int w = tid >> 6, lane = tid & 63;
  const int e = (w & 1) * 64 + lane;
  const int d0 = (w >> 1) * 64;
  float acc[64];
  #pragma unroll
  for (int i = 0; i < 64; ++i) acc[i] = 0.f;
  for (int t = 0; t < CHK_; ++t){
    const float vv = vl[e][t];
    const float4* kr = (const float4*)(&kex[t][d0]);
    #pragma unroll
    for (int i4 = 0; i4 < 16; ++i4){
      float4 kk = kr[i4];
      acc[i4*4+0] = fmaf(vv, kk.x, acc[i4*4+0]);
      acc[i4*4+1] = fmaf(vv, kk.y, acc[i4*4+1]);
      acc[i4*4+2] = fmaf(vv, kk.z, acc[i4*4+2]);
      acc[i4*4+3] = fmaf(vv, kk.w, acc[i4*4+3]);
    }
  }
  const size_t ob = (((size_t)(b * HKV_ + kv) * NC_ + c) * D_ + e) * D_ + d0;
  #pragma unroll
  for (int i8 = 0; i8 < 8; ++i8){
    ushortx8 o;
    #pragma unroll
    for (int u = 0; u < 8; ++u) o[u] = f2b(acc[i8*8 + u]);
    *(ushortx8*)(SSt + ob + i8*8) = o;
  }
}

// ---------------- elementwise scan over chunks (in place: dS -> S_start) ----------------
__global__ void k_scan(u16* __restrict__ SSt, const float* __restrict__ dec){
  const int eg = blockIdx.x, kv = blockIdx.y, b = blockIdx.z;
  const int tid = threadIdx.x;
  const int e = eg * 8 + (tid >> 5);
  const int d4 = (tid & 31) * 4;
  const size_t base  = ((size_t)(b * HKV_ + kv) * NC_) * D_ * D_ + (size_t)e * D_ + d4;
  const size_t dbase = ((size_t)(b * HKV_ + kv) * NC_) * D_ + d4;
  float s0 = 0.f, s1 = 0.f, s2 = 0.f, s3 = 0.f;
  #pragma unroll 4
  for (int c = 0; c < NC_; ++c){
    const size_t off = base + (size_t)c * (D_ * D_);
    ushort4 dv = *(ushort4*)(SSt + off);
    float4 dc = *(const float4*)(dec + dbase + (size_t)c * D_);
    ushort4 wr;
    wr.x = f2b(s0); wr.y = f2b(s1); wr.z = f2b(s2); wr.w = f2b(s3);
    *(ushort4*)(SSt + off) = wr;
    s0 = s0 * dc.x + b2f(dv.x);
    s1 = s1 * dc.y + b2f(dv.y);
    s2 = s2 * dc.z + b2f(dv.z);
    s3 = s3 * dc.w + b2f(dv.w);
  }
}

// ---------------- output, per-kv blocks: 4 heads share Sb/Ke/G ----------------
#define L_SB   0
#define L_KE0  16384
#define L_KE1  18432
#define L_QEF  22528
#define L_QE1  38912
#define L_AM   47104
#define L_G15  51200
__global__ void __launch_bounds__(512)
k_out2(const u16* __restrict__ qp, const u16* __restrict__ kp,
       const float* __restrict__ G, const u16* __restrict__ vT,
       const u16* __restrict__ SSt, float* __restrict__ out){
  extern __shared__ u16 lds[];
  float* G15f = (float*)(lds + L_G15);
  const int c = blockIdx.x, kv = blockIdx.y, b = blockIdx.z;
  const int tid = threadIdx.x, wid = tid >> 6, lane = tid & 63;
  const int hh = wid >> 1, sub = wid & 1;
  const int s0 = c * CHK_;
  const int lr = lane & 15, lk = (lane >> 4) * 8;
  const size_t gb = ((size_t)b * S_ + s0) * NKV_ + kv * D_;
  const size_t qb0 = ((size_t)b * S_ + s0) * DM_ + (kv * 4) * D_;
  const size_t vb = ((size_t)(b * HKV_ + kv) * D_) * S_ + s0;

  {
    const u16* src = SSt + (((size_t)(b * HKV_ + kv) * NC_ + c) * (D_ * D_));
    #pragma unroll
    for (int is = 0; is < 4; ++is){
      const int fo = is * 4096 + wid * 512;
      ASYNC16(src + fo + lane * 8, lds + L_SB + fo);
    }
  }
  if (tid < 128) G15f[tid] = G[gb + (size_t)15 * NKV_ + tid];
  __syncthreads();

  for (int idx = tid; idx < 32 * 128; idx += 512){
    const int t = idx >> 7, d = idx & 127;
    const float Gt = G[gb + (size_t)t * NKV_ + d];
    const float kf = b2f(kp[gb + (size_t)t * NKV_ + d]);
    const float eGt = __expf(Gt);
    float qv[4];
    #pragma unroll
    for (int q4 = 0; q4 < 4; ++q4) qv[q4] = b2f(qp[qb0 + (size_t)t * DM_ + q4 * D_ + d]);
    #pragma unroll
    for (int q4 = 0; q4 < 4; ++q4) lds[L_QEF + q4 * 4096 + idx] = f2b(qv[q4] * eGt);
    if (t >= 16){
      const float r = __expf(Gt - G15f[d]);
      #pragma unroll
      for (int q4 = 0; q4 < 4; ++q4) lds[L_QE1 + q4 * 2048 + (t - 16) * 128 + d] = f2b(qv[q4] * r);
    }
    if (t < 16) lds[L_KE0 + idx] = f2b(kf * __expf(-Gt));
    lds[L_KE1 + idx] = f2b(kf * __expf(G15f[d] - Gt));
  }
  __syncthreads();

  const u16* QeF = lds + L_QEF + hh * 4096;
  const u16* Qe1 = lds + L_QE1 + hh * 2048;
  u16* Am = lds + L_AM + hh * 1024;
  if (sub == 0){
    f32x4 aU = {}, aL = {};
    #pragma unroll
    for (int kd = 0; kd < 4; ++kd){
      bf16x8 faU = ld8(&QeF[lr * 128 + kd * 32 + lk]);
      bf16x8 fbU = ld8(&lds[L_KE0 + lr * 128 + kd * 32 + lk]);
      aU = mfma16(faU, fbU, aU);
      bf16x8 faL = ld8(&Qe1[lr * 128 + kd * 32 + lk]);
      bf16x8 fbL = ld8(&lds[L_KE1 + (16 + lr) * 128 + kd * 32 + lk]);
      aL = mfma16(faL, fbL, aL);
    }
    #pragma unroll
    for (int r = 0; r < 4; ++r){
      const int rr = (lane >> 4) * 4 + r;
      float vU = aU[r]; if (lr > rr) vU = 0.f;
      Am[rr * 32 + lr] = f2b(vU);
      float vL = aL[r]; if (lr > rr) vL = 0.f;
      Am[(16 + rr) * 32 + 16 + lr] = f2b(vL);
    }
  } else {
    f32x4 aO = {};
    #pragma unroll
    for (int kd = 0; kd < 4; ++kd){
      bf16x8 fa = ld8(&Qe1[lr * 128 + kd * 32 + lk]);
      bf16x8 fb = ld8(&lds[L_KE1 + lr * 128 + kd * 32 + lk]);
      aO = mfma16(fa, fb, aO);
    }
    #pragma unroll
    for (int r = 0; r < 4; ++r){
      const int rr = (lane >> 4) * 4 + r;
      Am[(16 + rr) * 32 + lr] = f2b(aO[r]);
    }
    for (int i = lane; i < 256; i += 64) Am[(i >> 4) * 32 + 16 + (i & 15)] = 0;
  }
  __syncthreads();

  f32x4 o4[2][4] = {};
  const int ew = sub * 64;
  #pragma unroll
  for (int kd = 0; kd < 4; ++kd){
    bf16x8 fa0 = ld8(&QeF[(0  + lr) * 128 + kd * 32 + lk]);
    bf16x8 fa1 = ld8(&QeF[(16 + lr) * 128 + kd * 32 + lk]);
    #pragma unroll
    for (int j2 = 0; j2 < 4; ++j2){
      bf16x8 fb = ld8(&lds[L_SB + (ew + j2 * 16 + lr) * 128 + kd * 32 + lk]);
      o4[0][j2] = mfma16(fa0, fb, o4[0][j2]);
      o4[1][j2] = mfma16(fa1, fb, o4[1][j2]);
    }
  }
  {
    bf16x8 fa0 = ld8(&Am[lr * 32 + lk]);
    bf16x8 fa1 = ld8(&Am[(16 + lr) * 32 + lk]);
    #pragma unroll
    for (int j2 = 0; j2 < 4; ++j2){
      const u16* vr = vT + vb + (size_t)(ew + j2 * 16 + lr) * S_;
      bf16x8 fb = ld8(vr + lk);
      o4[0][j2] = mfma16(fa0, fb, o4[0][j2]);
      o4[1][j2] = mfma16(fa1, fb, o4[1][j2]);
    }
  }
  const int hD = (kv * 4 + hh) * D_;
  #pragma unroll
  for (int i2 = 0; i2 < 2; ++i2)
    #pragma unroll
    for (int j2 = 0; j2 < 4; ++j2)
      #pragma unroll
      for (int r = 0; r < 4; ++r){
        const int t = i2 * 16 + (lane >> 4) * 4 + r;
        const int e = ew + j2 * 16 + lr;
        out[((size_t)b * S_ + s0 + t) * DM_ + hD + e] = o4[i2][j2][r];
      }
}

// ---------------- host launch ----------------
extern "C" void kernel_launch(void* const* d_in, const int* in_sizes, int n_in,
                              void* d_out, int out_size, void* d_ws, size_t ws_size,
                              hipStream_t stream){
  const float* hs = (const float*)d_in[0];
  const float* Wq = (const float*)d_in[1];
  const float* bq = (const float*)d_in[2];
  const float* Wk = (const float*)d_in[3];
  const float* bk = (const float*)d_in[4];
  const float* Wv = (const float*)d_in[5];
  const float* bv = (const float*)d_in[6];
  char* ws = (char*)d_ws;
  u16*   hsb = (u16*)(ws);
  u16*   wcb = (u16*)(ws + 16777216);
  u16*   qp  = (u16*)(ws + 29360128);
  u16*   kp  = (u16*)(ws + 46137344);
  float* gG  = (float*)(ws + 50331648);
  u16*   vT  = (u16*)(ws + 58720256);
  float* dec = (float*)(ws + 62914560);
  u16*   SSt = (u16*)(ws + 63176704);
  float* out = (float*)d_out;

  hipFuncSetAttribute((const void*)k_out2,
                      hipFuncAttributeMaxDynamicSharedMemorySize, 102912);

  k_cvt_all<<<dim3(7168), 256, 0, stream>>>(hs, Wq, Wk, Wv, hsb, wcb);
  k_gemm<<<dim3(24, 32), 256, 0, stream>>>(hsb, wcb, bq, bk, bv, qp, kp, gG, vT);
  k_cumsum<<<dim3(NC_, B_), 512, 0, stream>>>(gG, dec);
  k_dstate<<<dim3(NC_, HKV_, B_), 256, 0, stream>>>(kp, gG, vT, SSt);
  k_scan<<<dim3(16, HKV_, B_), 256, 0, stream>>>(SSt, dec);
  k_out2<<<dim3(NC_, HKV_, B_), 512, 102912, stream>>>(qp, kp, gG, vT, SSt, out);
}

// Round 9
// 151.643 us; speedup vs baseline: 1.7763x; 1.0016x over previous
//
#include <hip/hip_runtime.h>
#include <math.h>

// ---- problem constants ----
#define B_ 2
#define S_ 2048
#define DM_ 2048
#define H_ 16
#define HKV_ 4
#define D_ 128
#define NKV_ 512           // HKV*D
#define M_ 4096            // B*S
#define CHK_ 32            // chunk length
#define NC_ 64             // S/CHK
#define SCALE_ 0.08838834764831845f
#define CLAMP_ 0.95f

typedef unsigned short u16;
typedef u16 ushortx8 __attribute__((ext_vector_type(8)));
typedef __bf16 bf16x8 __attribute__((ext_vector_type(8)));
typedef float f32x4 __attribute__((ext_vector_type(4)));

#define ASYNC16(gsrc, ldst) \
  __builtin_amdgcn_global_load_lds((const __attribute__((address_space(1))) void*)(gsrc), \
                                   (__attribute__((address_space(3))) void*)(ldst), 16, 0, 0)
#define SBAR()    __builtin_amdgcn_s_barrier()
#define WAITV(n)  asm volatile("s_waitcnt vmcnt(" #n ")" ::: "memory")

__device__ __forceinline__ u16 f2b(float x){
  unsigned u = __float_as_uint(x);
  return (u16)((u + 0x7FFFu + ((u >> 16) & 1u)) >> 16);
}
__device__ __forceinline__ float b2f(u16 h){
  return __uint_as_float(((unsigned)h) << 16);
}
__device__ __forceinline__ bf16x8 ld8(const u16* p){
  return __builtin_bit_cast(bf16x8, *(const ushortx8*)p);
}
__device__ __forceinline__ f32x4 mfma16(bf16x8 a, bf16x8 b, f32x4 c){
  return __builtin_amdgcn_mfma_f32_16x16x32_bf16(a, b, c, 0, 0, 0);
}

// ---------------- fused f32 -> bf16 convert for hs + Wq + Wk + Wv ----------------
__global__ void k_cvt_all(const float* __restrict__ hs, const float* __restrict__ Wq,
                          const float* __restrict__ Wk, const float* __restrict__ Wv,
                          u16* __restrict__ hsb, u16* __restrict__ wcb){
  int i = blockIdx.x * blockDim.x + threadIdx.x;  // 8-elem unit
  const float* src; u16* dst;
  if (i < 1048576)      { src = hs + (size_t)i * 8;               dst = hsb + (size_t)i * 8; }
  else if (i < 1572864) { int j = i - 1048576; src = Wq + (size_t)j * 8; dst = wcb + (size_t)j * 8; }
  else if (i < 1703936) { int j = i - 1572864; src = Wk + (size_t)j * 8; dst = wcb + 4194304 + (size_t)j * 8; }
  else                  { int j = i - 1703936; src = Wv + (size_t)j * 8; dst = wcb + 5242880 + (size_t)j * 8; }
  const float4* p = (const float4*)src;
  float4 a = p[0], c = p[1];
  ushortx8 o;
  o[0]=f2b(a.x); o[1]=f2b(a.y); o[2]=f2b(a.z); o[3]=f2b(a.w);
  o[4]=f2b(c.x); o[5]=f2b(c.y); o[6]=f2b(c.z); o[7]=f2b(c.w);
  *(ushortx8*)dst = o;
}

// ---------------- 128x128x32 GEMM, 3-slot LDS ring + XOR-swizzled slots ----------------
// LDS slot-position p at row r holds data-slot p^(r&3) (16B granules, involution).
// Stage: linear LDS dest, source col pre-permuted. Read: position (lane>>4)^(lr&3).
__launch_bounds__(256, 2)
__global__ void k_gemm(const u16* __restrict__ A, const u16* __restrict__ W,
                       const float* __restrict__ bq, const float* __restrict__ bk,
                       const float* __restrict__ bv,
                       u16* __restrict__ qp, u16* __restrict__ kp,
                       float* __restrict__ gG, u16* __restrict__ vT){
  __shared__ u16 L[3 * 8192];          // 48 KiB
  const int tid = threadIdx.x;
  const int wid = tid >> 6, lane = tid & 63;
  const int m0 = blockIdx.y * 128, n0 = blockIdx.x * 128;
  const int wr = (wid >> 1) * 64, wc = (wid & 1) * 64;
  const int lr = lane & 15;

  int offA[4], offB[4];
  #pragma unroll
  for (int m = 0; m < 4; ++m)
    offA[m] = (wr + m * 16 + lr) * 32 + (((lane >> 4) ^ (lr & 3)) << 3);
  #pragma unroll
  for (int n = 0; n < 4; ++n)
    offB[n] = (wc + n * 16 + lr) * 32 + (((lane >> 4) ^ (lr & 3)) << 3);

  // staging: per-lane source; LDS position (lane&3) at row (wid*32+lane/4) gets
  // data-slot (lane&3)^(row&3) -> pre-permuted source column
  const int srow = wid * 32 + (lane >> 2);
  const int scol = (((lane & 3) ^ ((lane >> 2) & 3)) << 3);
  const u16* gA = A + (size_t)(m0 + srow) * DM_ + scol;
  const u16* gW = W + (size_t)(n0 + srow) * DM_ + scol;
  const int fo = wid * 1024;

#define STG(db, kk0) \
  ASYNC16(gA + (kk0),             L + (db) + fo); \
  ASYNC16(gA + 16 * DM_ + (kk0),  L + (db) + fo + 512); \
  ASYNC16(gW + (kk0),             L + (db) + 4096 + fo); \
  ASYNC16(gW + 16 * DM_ + (kk0),  L + (db) + 4096 + fo + 512)

  f32x4 acc[4][4] = {};

  // prologue: tile0 -> slot0, tile1 -> slot1
  STG(0, 0);
  STG(8192, 32);

  int sl_cur = 0, sl_st = 16384;
  for (int kt = 0; kt < 64; ++kt){
    WAITV(4);          // tile kt's 4 loads (issued at kt-2) retired
    SBAR();
    const int k2 = ((kt + 2 < 64) ? kt + 2 : 63) * 32;
    STG(sl_st, k2);    // issue-early; lands in slot (kt+2)%3
    bf16x8 af[4], bfv[4];
    #pragma unroll
    for (int m = 0; m < 4; ++m) af[m]  = ld8(L + sl_cur + offA[m]);
    #pragma unroll
    for (int n = 0; n < 4; ++n) bfv[n] = ld8(L + sl_cur + 4096 + offB[n]);
    #pragma unroll
    for (int m = 0; m < 4; ++m)
      #pragma unroll
      for (int n = 0; n < 4; ++n)
        acc[m][n] = mfma16(af[m], bfv[n], acc[m][n]);
    sl_cur = (sl_cur == 16384) ? 0 : sl_cur + 8192;
    sl_st  = (sl_st  == 16384) ? 0 : sl_st  + 8192;
  }
#undef STG

  // ---- epilogue: per-region bias + activation (R1-proven) ----
  const int lg4 = lane >> 4;
  const int tn = blockIdx.x;
  if (tn < 16){                       // ---- q region: relu * scale ----
    #pragma unroll
    for (int i = 0; i < 4; ++i){
      const int rb = m0 + wr + i*16 + lg4*4;
      #pragma unroll
      for (int j = 0; j < 4; ++j){
        const int col = n0 + wc + j*16 + lr;
        const float bb = bq[col];
        #pragma unroll
        for (int r = 0; r < 4; ++r){
          float q = fmaxf(acc[i][j][r] + bb, 0.f) * SCALE_;
          qp[(size_t)(rb + r) * DM_ + col] = f2b(q);
        }
      }
    }
  } else if (tn < 20){                // ---- k region ----
    #pragma unroll
    for (int i = 0; i < 4; ++i){
      const int rb = m0 + wr + i*16 + lg4*4;
      #pragma unroll
      for (int j = 0; j < 4; ++j){
        const int cc = n0 - DM_ + wc + j*16 + lr;
        const float bb = bk[cc];
        #pragma unroll
        for (int r = 0; r < 4; ++r){
          float x = acc[i][j][r] + bb;
          float kf = fminf(1.f / (1.f + __expf(-x)), CLAMP_);
          kp[(size_t)(rb + r) * NKV_ + cc] = f2b(kf);
          gG[(size_t)(rb + r) * NKV_ + cc] = log1pf(-kf);
        }
      }
    }
  } else {                            // ---- v region: write transposed vT[b][kv][e][s] ----
    #pragma unroll
    for (int i = 0; i < 4; ++i){
      const int rb = m0 + wr + i*16 + lg4*4;
      const int bb_ = rb >> 11;
      const int srw = rb & 2047;
      #pragma unroll
      for (int j = 0; j < 4; ++j){
        const int cc = n0 - DM_ - NKV_ + wc + j*16 + lr;
        const float bias = bv[cc];
        const int kv = cc >> 7, e = cc & 127;
        ushort4 pk;
        pk.x = f2b(acc[i][j][0] + bias);
        pk.y = f2b(acc[i][j][1] + bias);
        pk.z = f2b(acc[i][j][2] + bias);
        pk.w = f2b(acc[i][j][3] + bias);
        *(ushort4*)(vT + (((size_t)(bb_ * HKV_ + kv) * D_ + e) * S_ + srw)) = pk;
      }
    }
  }
}

// ---------------- per-chunk inclusive cumsum of g (in place) + chunk decay ----------------
__global__ void k_cumsum(float* __restrict__ g, float* __restrict__ dec){
  const int c = blockIdx.x, b = blockIdx.z;
  const int col = blockIdx.y * 256 + threadIdx.x;   // 512 = kv*128+d
  const size_t base = ((size_t)b * S_ + (size_t)c * CHK_) * NKV_ + col;
  float v[CHK_];
  #pragma unroll
  for (int t = 0; t < CHK_; ++t) v[t] = g[base + (size_t)t * NKV_];
  float acc = 0.f;
  #pragma unroll
  for (int t = 0; t < CHK_; ++t){ acc += v[t]; v[t] = acc; }
  #pragma unroll
  for (int t = 0; t < CHK_; ++t) g[base + (size_t)t * NKV_] = v[t];
  const int kv = col >> 7, d = col & 127;
  dec[(((size_t)b * HKV_ + kv) * NC_ + c) * D_ + d] = __expf(acc);
}

// ---------------- per-chunk state contribution:  SSt[c][e][d] = sum_t v[t][e]*kf[t][d]*exp(G31-G_t) ----------------
__launch_bounds__(256, 2)
__global__ void k_dstate(const u16* __restrict__ kp, const float* __restrict__ G,
                         const u16* __restrict__ vT, u16* __restrict__ SSt){
  __shared__ float kex[CHK_][D_];
  __shared__ float vl[D_][CHK_ + 1];
  const int c = blockIdx.x, kv = blockIdx.y, b = blockIdx.z;
  const int tid = threadIdx.x;
  const int s0 = c * CHK_;
  const size_t gbase = ((size_t)b * S_ + s0) * NKV_ + kv * D_;
  for (int idx = tid; idx < CHK_ * D_; idx += 256){
    const int t = idx >> 7, d = idx & 127;
    const float Gt  = G[gbase + (size_t)t  * NKV_ + d];
    const float G31 = G[gbase + (size_t)31 * NKV_ + d];
    const float kf = b2f(kp[gbase + (size_t)t * NKV_ + d]);
    kex[t][d] = kf * __expf(G31 - Gt);
  }
  const size_t vbase = ((size_t)(b * HKV_ + kv) * D_) * S_ + s0;
  for (int idx = tid; idx < 512; idx += 256){
    const int e = idx >> 2, t8 = (idx & 3) * 8;
    ushortx8 vv = *(const ushortx8*)(vT + vbase + (size_t)e * S_ + t8);
    #pragma unroll
    for (int u = 0; u < 8; ++u) vl[e][t8 + u] = b2f(vv[u]);
  }
  __syncthreads();
  const int w = tid >> 6, lane = tid & 63;
  const int e = (w & 1) * 64 + lane;
  const int d0 = (w >> 1) * 64;
  float acc[64];
  #pragma unroll
  for (int i = 0; i < 64; ++i) acc[i] = 0.f;
  for (int t = 0; t < CHK_; ++t){
    const float vv = vl[e][t];
    const float4* kr = (const float4*)(&kex[t][d0]);
    #pragma unroll
    for (int i4 = 0; i4 < 16; ++i4){
      float4 kk = kr[i4];
      acc[i4*4+0] = fmaf(vv, kk.x, acc[i4*4+0]);
      acc[i4*4+1] = fmaf(vv, kk.y, acc[i4*4+1]);
      acc[i4*4+2] = fmaf(vv, kk.z, acc[i4*4+2]);
      acc[i4*4+3] = fmaf(vv, kk.w, acc[i4*4+3]);
    }
  }
  const size_t ob = (((size_t)(b * HKV_ + kv) * NC_ + c) * D_ + e) * D_ + d0;
  #pragma unroll
  for (int i8 = 0; i8 < 8; ++i8){
    ushortx8 o;
    #pragma unroll
    for (int u = 0; u < 8; ++u) o[u] = f2b(acc[i8*8 + u]);
    *(ushortx8*)(SSt + ob + i8*8) = o;
  }
}

// ---------------- elementwise scan over chunks (256 blocks x 128 thr, 1/CU) ----------------
__global__ void k_scan(u16* __restrict__ SSt, const float* __restrict__ dec){
  const int eg = blockIdx.x, kv = blockIdx.y, b = blockIdx.z;
  const int tid = threadIdx.x;
  const int e = eg * 4 + (tid >> 5);
  const int d4 = (tid & 31) * 4;
  const size_t base  = ((size_t)(b * HKV_ + kv) * NC_) * D_ * D_ + (size_t)e * D_ + d4;
  const size_t dbase = ((size_t)(b * HKV_ + kv) * NC_) * D_ + d4;
  float s0 = 0.f, s1 = 0.f, s2 = 0.f, s3 = 0.f;
  #pragma unroll 4
  for (int c = 0; c < NC_; ++c){
    const size_t off = base + (size_t)c * (D_ * D_);
    ushort4 dv = *(ushort4*)(SSt + off);
    float4 dc = *(const float4*)(dec + dbase + (size_t)c * D_);
    ushort4 wr;
    wr.x = f2b(s0); wr.y = f2b(s1); wr.z = f2b(s2); wr.w = f2b(s3);
    *(ushort4*)(SSt + off) = wr;
    s0 = s0 * dc.x + b2f(dv.x);
    s1 = s1 * dc.y + b2f(dv.y);
    s2 = s2 * dc.z + b2f(dv.z);
    s3 = s3 * dc.w + b2f(dv.w);
  }
}

// ---------------- output, per-kv blocks: 4 heads share Sb/Ke/G ----------------
#define L_SB   0
#define L_KE0  16384
#define L_KE1  18432
#define L_QEF  22528
#define L_QE1  38912
#define L_AM   47104
#define L_G15  51200
__global__ void __launch_bounds__(512)
k_out2(const u16* __restrict__ qp, const u16* __restrict__ kp,
       const float* __restrict__ G, const u16* __restrict__ vT,
       const u16* __restrict__ SSt, float* __restrict__ out){
  extern __shared__ u16 lds[];
  float* G15f = (float*)(lds + L_G15);
  const int c = blockIdx.x, kv = blockIdx.y, b = blockIdx.z;
  const int tid = threadIdx.x, wid = tid >> 6, lane = tid & 63;
  const int hh = wid >> 1, sub = wid & 1;
  const int s0 = c * CHK_;
  const int lr = lane & 15, lk = (lane >> 4) * 8;
  const size_t gb = ((size_t)b * S_ + s0) * NKV_ + kv * D_;
  const size_t qb0 = ((size_t)b * S_ + s0) * DM_ + (kv * 4) * D_;
  const size_t vb = ((size_t)(b * HKV_ + kv) * D_) * S_ + s0;

  {
    const u16* src = SSt + (((size_t)(b * HKV_ + kv) * NC_ + c) * (D_ * D_));
    #pragma unroll
    for (int is = 0; is < 4; ++is){
      const int fo = is * 4096 + wid * 512;
      ASYNC16(src + fo + lane * 8, lds + L_SB + fo);
    }
  }
  if (tid < 128) G15f[tid] = G[gb + (size_t)15 * NKV_ + tid];
  __syncthreads();

  for (int idx = tid; idx < 32 * 128; idx += 512){
    const int t = idx >> 7, d = idx & 127;
    const float Gt = G[gb + (size_t)t * NKV_ + d];
    const float kf = b2f(kp[gb + (size_t)t * NKV_ + d]);
    const float eGt = __expf(Gt);
    float qv[4];
    #pragma unroll
    for (int q4 = 0; q4 < 4; ++q4) qv[q4] = b2f(qp[qb0 + (size_t)t * DM_ + q4 * D_ + d]);
    #pragma unroll
    for (int q4 = 0; q4 < 4; ++q4) lds[L_QEF + q4 * 4096 + idx] = f2b(qv[q4] * eGt);
    if (t >= 16){
      const float r = __expf(Gt - G15f[d]);
      #pragma unroll
      for (int q4 = 0; q4 < 4; ++q4) lds[L_QE1 + q4 * 2048 + (t - 16) * 128 + d] = f2b(qv[q4] * r);
    }
    if (t < 16) lds[L_KE0 + idx] = f2b(kf * __expf(-Gt));
    lds[L_KE1 + idx] = f2b(kf * __expf(G15f[d] - Gt));
  }
  __syncthreads();

  const u16* QeF = lds + L_QEF + hh * 4096;
  const u16* Qe1 = lds + L_QE1 + hh * 2048;
  u16* Am = lds + L_AM + hh * 1024;
  if (sub == 0){
    f32x4 aU = {}, aL = {};
    #pragma unroll
    for (int kd = 0; kd < 4; ++kd){
      bf16x8 faU = ld8(&QeF[lr * 128 + kd * 32 + lk]);
      bf16x8 fbU = ld8(&lds[L_KE0 + lr * 128 + kd * 32 + lk]);
      aU = mfma16(faU, fbU, aU);
      bf16x8 faL = ld8(&Qe1[lr * 128 + kd * 32 + lk]);
      bf16x8 fbL = ld8(&lds[L_KE1 + (16 + lr) * 128 + kd * 32 + lk]);
      aL = mfma16(faL, fbL, aL);
    }
    #pragma unroll
    for (int r = 0; r < 4; ++r){
      const int rr = (lane >> 4) * 4 + r;
      float vU = aU[r]; if (lr > rr) vU = 0.f;
      Am[rr * 32 + lr] = f2b(vU);
      float vL = aL[r]; if (lr > rr) vL = 0.f;
      Am[(16 + rr) * 32 + 16 + lr] = f2b(vL);
    }
  } else {
    f32x4 aO = {};
    #pragma unroll
    for (int kd = 0; kd < 4; ++kd){
      bf16x8 fa = ld8(&Qe1[lr * 128 + kd * 32 + lk]);
      bf16x8 fb = ld8(&lds[L_KE1 + lr * 128 + kd * 32 + lk]);
      aO = mfma16(fa, fb, aO);
    }
    #pragma unroll
    for (int r = 0; r < 4; ++r){
      const int rr = (lane >> 4) * 4 + r;
      Am[(16 + rr) * 32 + lr] = f2b(aO[r]);
    }
    for (int i = lane; i < 256; i += 64) Am[(i >> 4) * 32 + 16 + (i & 15)] = 0;
  }
  __syncthreads();

  f32x4 o4[2][4] = {};
  const int ew = sub * 64;
  #pragma unroll
  for (int kd = 0; kd < 4; ++kd){
    bf16x8 fa0 = ld8(&QeF[(0  + lr) * 128 + kd * 32 + lk]);
    bf16x8 fa1 = ld8(&QeF[(16 + lr) * 128 + kd * 32 + lk]);
    #pragma unroll
    for (int j2 = 0; j2 < 4; ++j2){
      bf16x8 fb = ld8(&lds[L_SB + (ew + j2 * 16 + lr) * 128 + kd * 32 + lk]);
      o4[0][j2] = mfma16(fa0, fb, o4[0][j2]);
      o4[1][j2] = mfma16(fa1, fb, o4[1][j2]);
    }
  }
  {
    bf16x8 fa0 = ld8(&Am[lr * 32 + lk]);
    bf16x8 fa1 = ld8(&Am[(16 + lr) * 32 + lk]);
    #pragma unroll
    for (int j2 = 0; j2 < 4; ++j2){
      const u16* vr = vT + vb + (size_t)(ew + j2 * 16 + lr) * S_;
      bf16x8 fb = ld8(vr + lk);
      o4[0][j2] = mfma16(fa0, fb, o4[0][j2]);
      o4[1][j2] = mfma16(fa1, fb, o4[1][j2]);
    }
  }
  const int hD = (kv * 4 + hh) * D_;
  #pragma unroll
  for (int i2 = 0; i2 < 2; ++i2)
    #pragma unroll
    for (int j2 = 0; j2 < 4; ++j2)
      #pragma unroll
      for (int r = 0; r < 4; ++r){
        const int t = i2 * 16 + (lane >> 4) * 4 + r;
        const int e = ew + j2 * 16 + lr;
        out[((size_t)b * S_ + s0 + t) * DM_ + hD + e] = o4[i2][j2][r];
      }
}

// ---------------- host launch ----------------
extern "C" void kernel_launch(void* const* d_in, const int* in_sizes, int n_in,
                              void* d_out, int out_size, void* d_ws, size_t ws_size,
                              hipStream_t stream){
  const float* hs = (const float*)d_in[0];
  const float* Wq = (const float*)d_in[1];
  const float* bq = (const float*)d_in[2];
  const float* Wk = (const float*)d_in[3];
  const float* bk = (const float*)d_in[4];
  const float* Wv = (const float*)d_in[5];
  const float* bv = (const float*)d_in[6];
  char* ws = (char*)d_ws;
  u16*   hsb = (u16*)(ws);
  u16*   wcb = (u16*)(ws + 16777216);
  u16*   qp  = (u16*)(ws + 29360128);
  u16*   kp  = (u16*)(ws + 46137344);
  float* gG  = (float*)(ws + 50331648);
  u16*   vT  = (u16*)(ws + 58720256);
  float* dec = (float*)(ws + 62914560);
  u16*   SSt = (u16*)(ws + 63176704);
  float* out = (float*)d_out;

  hipFuncSetAttribute((const void*)k_out2,
                      hipFuncAttributeMaxDynamicSharedMemorySize, 102912);

  k_cvt_all<<<dim3(7168), 256, 0, stream>>>(hs, Wq, Wk, Wv, hsb, wcb);
  k_gemm<<<dim3(24, 32), 256, 0, stream>>>(hsb, wcb, bq, bk, bv, qp, kp, gG, vT);
  k_cumsum<<<dim3(NC_, 2, B_), 256, 0, stream>>>(gG, dec);
  k_dstate<<<dim3(NC_, HKV_, B_), 256, 0, stream>>>(kp, gG, vT, SSt);
  k_scan<<<dim3(32, HKV_, B_), 128, 0, stream>>>(SSt, dec);
  k_out2<<<dim3(NC_, HKV_, B_), 512, 102912, stream>>>(qp, kp, gG, vT, SSt, out);
}